// Round 1
// baseline (90.368 us; speedup 1.0000x reference)
//
#include <hip/hip_runtime.h>
#include <math.h>

#define EPSF    1e-6f
#define B_N     4096
#define D_N     128
#define P_N     128
#define NPAIRS  (P_N * (P_N - 1) / 2)   // 8128
#define ITERS   10
#define MAXNORM 0.99999f                 // (1 - 1e-5) / sqrt(c), c = 1

__device__ __forceinline__ float wred64(float v) {
    v += __shfl_xor(v, 1);
    v += __shfl_xor(v, 2);
    v += __shfl_xor(v, 4);
    v += __shfl_xor(v, 8);
    v += __shfl_xor(v, 16);
    v += __shfl_xor(v, 32);
    return v;
}

__device__ __forceinline__ double wred64d(double v) {
    v += __shfl_xor(v, 1);
    v += __shfl_xor(v, 2);
    v += __shfl_xor(v, 4);
    v += __shfl_xor(v, 8);
    v += __shfl_xor(v, 16);
    v += __shfl_xor(v, 32);
    return v;
}

// ---------------------------------------------------------------------------
// Kernel A: expmap0 per row (wave per row), also emit x2 = ||xp||^2
// ---------------------------------------------------------------------------
__global__ __launch_bounds__(256) void expmap_kernel(
        const float* __restrict__ reps,
        float* __restrict__ xp,
        float* __restrict__ x2) {
    int row  = blockIdx.x * 4 + (threadIdx.x >> 6);
    int lane = threadIdx.x & 63;
    if (row >= B_N) return;
    float2 v = ((const float2*)(reps + row * D_N))[lane];
    float n2 = wred64(v.x * v.x + v.y * v.y);
    float n  = fmaxf(sqrtf(n2), EPSF);
    float s  = tanhf(n) / n;
    float2 o; o.x = v.x * s; o.y = v.y * s;
    ((float2*)(xp + row * D_N))[lane] = o;
    float xs = wred64(o.x * o.x + o.y * o.y);
    if (lane == 0) x2[row] = xs;
}

// ---------------------------------------------------------------------------
// Kernel B: one block per prototype group; full Karcher-mean loop locally.
// 256 threads = 4 waves; each wave holds the full mu (float2 per lane),
// processes members wave-strided, combines partial sums through LDS.
// ---------------------------------------------------------------------------
__global__ __launch_bounds__(256) void proto_kernel(
        const float* __restrict__ xp,
        const float* __restrict__ x2g,
        const int*   __restrict__ targets,
        float* __restrict__ mu_out) {
    __shared__ int   mlist[B_N];
    __shared__ int   s_n;
    __shared__ float part[4][D_N];

    const int p    = blockIdx.x;
    const int tid  = threadIdx.x;
    const int wave = tid >> 6;
    const int lane = tid & 63;

    // --- deterministic (b-ordered) member list build via ballot, wave 0 only
    if (wave == 0) {
        int base = 0;
        for (int b0 = 0; b0 < B_N; b0 += 64) {
            int b = b0 + lane;
            bool m = (targets[b] == p);
            unsigned long long mask = __ballot(m);
            if (m) {
                int pos = base + __popcll(mask & ((1ULL << lane) - 1ULL));
                mlist[pos] = b;
            }
            base += __popcll(mask);
        }
        if (lane == 0) s_n = base;
    }
    __syncthreads();

    const int   n       = s_n;
    const float inv_cnt = 1.0f / fmaxf((float)n, 1.0f);

    // --- initial mu: Euclidean mean of members, then project
    float2 acc; acc.x = 0.f; acc.y = 0.f;
    for (int t = wave; t < n; t += 4) {
        float2 v = ((const float2*)(xp + mlist[t] * D_N))[lane];
        acc.x += v.x; acc.y += v.y;
    }
    part[wave][2 * lane]     = acc.x;
    part[wave][2 * lane + 1] = acc.y;
    __syncthreads();
    float2 mu;
    mu.x = (part[0][2*lane]   + part[1][2*lane]   + part[2][2*lane]   + part[3][2*lane])   * inv_cnt;
    mu.y = (part[0][2*lane+1] + part[1][2*lane+1] + part[2][2*lane+1] + part[3][2*lane+1]) * inv_cnt;
    __syncthreads();
    {
        float m2    = wred64(mu.x * mu.x + mu.y * mu.y);
        float norm  = fmaxf(sqrtf(m2), EPSF);
        float fac   = fminf(1.0f, MAXNORM / norm);
        mu.x *= fac; mu.y *= fac;
    }
    float mu2 = wred64(mu.x * mu.x + mu.y * mu.y);

    // --- Karcher iterations
    for (int it = 0; it < ITERS; ++it) {
        float2 a; a.x = 0.f; a.y = 0.f;
        for (int t = wave; t < n; t += 4) {
            int m = mlist[t];
            float2 v = ((const float2*)(xp + m * D_N))[lane];
            float xy  = wred64(v.x * mu.x + v.y * mu.y);   // <x, mu>
            float xx2 = x2g[m];
            // diff = mobius_add(x, -mu):
            float ca  = 1.0f - 2.0f * xy + mu2;            // coef on x
            float cb  = 1.0f - xx2;                        // coef on y=-mu
            float den = 1.0f - 2.0f * xy + xx2 * mu2;
            float inv = 1.0f / fmaxf(den, EPSF);
            a.x += (ca * v.x - cb * mu.x) * inv;
            a.y += (ca * v.y - cb * mu.y) * inv;
        }
        part[wave][2 * lane]     = a.x;
        part[wave][2 * lane + 1] = a.y;
        __syncthreads();
        float2 md;
        md.x = (part[0][2*lane]   + part[1][2*lane]   + part[2][2*lane]   + part[3][2*lane])   * inv_cnt;
        md.y = (part[0][2*lane+1] + part[1][2*lane+1] + part[2][2*lane+1] + part[3][2*lane+1]) * inv_cnt;
        __syncthreads();

        // mu <- project(mobius_add(mu, md))
        float y2  = wred64(md.x * md.x + md.y * md.y);
        float xy  = wred64(mu.x * md.x + mu.y * md.y);
        float ca  = 1.0f + 2.0f * xy + y2;
        float cb  = 1.0f - mu2;
        float den = 1.0f + 2.0f * xy + mu2 * y2;
        float inv = 1.0f / fmaxf(den, EPSF);
        float2 t;
        t.x = (ca * mu.x + cb * md.x) * inv;
        t.y = (ca * mu.y + cb * md.y) * inv;
        float t2   = wred64(t.x * t.x + t.y * t.y);
        float norm = fmaxf(sqrtf(t2), EPSF);
        float fac  = fminf(1.0f, MAXNORM / norm);
        mu.x = t.x * fac; mu.y = t.y * fac;
        mu2  = wred64(mu.x * mu.x + mu.y * mu.y);
    }

    // final project_to_ball (reference applies it once more)
    {
        float norm = fmaxf(sqrtf(mu2), EPSF);
        float fac  = fminf(1.0f, MAXNORM / norm);
        mu.x *= fac; mu.y *= fac;
    }
    if (wave == 0) {
        ((float2*)(mu_out + p * D_N))[lane] = mu;
    }
}

// ---------------------------------------------------------------------------
// Kernel C: Poincare distance for each upper-triangular pair (wave per pair)
// ---------------------------------------------------------------------------
__global__ __launch_bounds__(256) void dist_kernel(
        const float* __restrict__ mu,
        float* __restrict__ dB) {
    int k    = blockIdx.x * 4 + (threadIdx.x >> 6);
    int lane = threadIdx.x & 63;
    if (k >= NPAIRS) return;

    // map k -> (i, j), i < j, row-major upper triangle
    int i = (int)((float)P_N - 0.5f -
                  sqrtf(((float)P_N - 0.5f) * ((float)P_N - 0.5f) - 2.0f * (float)k));
    if (i < 0) i = 0;
    while ((i + 1) * (2 * P_N - i - 2) / 2 <= k) ++i;
    while (i * (2 * P_N - i - 1) / 2 > k) --i;
    int j = k - i * (2 * P_N - i - 1) / 2 + i + 1;

    float2 a = ((const float2*)(mu + i * D_N))[lane];
    float2 b = ((const float2*)(mu + j * D_N))[lane];
    float dx = a.x - b.x, dy = a.y - b.y;
    float d2  = wred64(dx * dx + dy * dy);
    float xi2 = wred64(a.x * a.x + a.y * a.y);
    float xj2 = wred64(b.x * b.x + b.y * b.y);
    float ai = fmaxf(1.0f - xi2, EPSF);
    float aj = fmaxf(1.0f - xj2, EPSF);
    float z  = 1.0f + 2.0f * d2 / fmaxf(ai * aj, EPSF);
    z = fmaxf(z, 1.0f + EPSF);
    float dist = acoshf(z);
    if (lane == 0) dB[k] = dist;
}

// ---------------------------------------------------------------------------
// Kernel D: Pearson correlation of dB with dT, single block
// ---------------------------------------------------------------------------
__global__ __launch_bounds__(256) void corr_kernel(
        const float* __restrict__ dB,
        const int*   __restrict__ dT,
        float* __restrict__ out) {
    __shared__ double sh[4][5];
    const int tid  = threadIdx.x;
    const int wave = tid >> 6;
    const int lane = tid & 63;

    double s1 = 0.0, s2 = 0.0, st = 0.0, st2 = 0.0, sbt = 0.0;
    for (int k = tid; k < NPAIRS; k += 256) {
        double b = (double)dB[k];
        double t = (double)dT[k];
        s1 += b; s2 += b * b; st += t; st2 += t * t; sbt += b * t;
    }
    s1  = wred64d(s1);
    s2  = wred64d(s2);
    st  = wred64d(st);
    st2 = wred64d(st2);
    sbt = wred64d(sbt);
    if (lane == 0) {
        sh[wave][0] = s1; sh[wave][1] = s2; sh[wave][2] = st;
        sh[wave][3] = st2; sh[wave][4] = sbt;
    }
    __syncthreads();
    if (tid == 0) {
        double t1 = 0, t2 = 0, t3 = 0, t4 = 0, t5 = 0;
        for (int w = 0; w < 4; ++w) {
            t1 += sh[w][0]; t2 += sh[w][1]; t3 += sh[w][2];
            t4 += sh[w][3]; t5 += sh[w][4];
        }
        const double n  = (double)NPAIRS;
        double mb  = t1 / n;
        double mt  = t3 / n;
        double cov = t5 - n * mb * mt;
        double vb  = t2 - n * mb * mb;
        double vt  = t4 - n * mt * mt;
        double corr = cov / sqrt(vb * vt);
        double res  = isnan(corr) ? 1.0 : (1.0 - corr);
        out[0] = (float)res;
    }
}

// ---------------------------------------------------------------------------
extern "C" void kernel_launch(void* const* d_in, const int* in_sizes, int n_in,
                              void* d_out, int out_size, void* d_ws, size_t ws_size,
                              hipStream_t stream) {
    const float* reps    = (const float*)d_in[0];
    const int*   targets = (const int*)d_in[1];
    const int*   dT      = (const int*)d_in[2];
    float* out = (float*)d_out;

    float* xp = (float*)d_ws;            // B*D          = 524288 floats
    float* x2 = xp + B_N * D_N;          // B            =   4096 floats
    float* mu = x2 + B_N;                // P*D          =  16384 floats
    float* dB = mu + P_N * D_N;          // NPAIRS       =   8128 floats
                                         // total ~2.2 MB of d_ws

    expmap_kernel<<<B_N / 4, 256, 0, stream>>>(reps, xp, x2);
    proto_kernel<<<P_N, 256, 0, stream>>>(xp, x2, targets, mu);
    dist_kernel<<<(NPAIRS + 3) / 4, 256, 0, stream>>>(mu, dB);
    corr_kernel<<<1, 256, 0, stream>>>(dB, dT, out);
}

// Round 2
// 88.163 us; speedup vs baseline: 1.0250x; 1.0250x over previous
//
#include <hip/hip_runtime.h>
#include <math.h>

#define EPSF    1e-6f
#define B_N     4096
#define D_N     128
#define P_N     128
#define NPAIRS  (P_N * (P_N - 1) / 2)   // 8128
#define ITERS   10
#define MAXNORM 0.99999f                 // (1 - 1e-5) / sqrt(c), c = 1

__device__ __forceinline__ float wred64(float v) {
    v += __shfl_xor(v, 1);
    v += __shfl_xor(v, 2);
    v += __shfl_xor(v, 4);
    v += __shfl_xor(v, 8);
    v += __shfl_xor(v, 16);
    v += __shfl_xor(v, 32);
    return v;
}

__device__ __forceinline__ double wred64d(double v) {
    v += __shfl_xor(v, 1);
    v += __shfl_xor(v, 2);
    v += __shfl_xor(v, 4);
    v += __shfl_xor(v, 8);
    v += __shfl_xor(v, 16);
    v += __shfl_xor(v, 32);
    return v;
}

// ---------------------------------------------------------------------------
// Kernel 1: deterministic counting sort of b-indices by group.
// Single block, 1024 threads = 16 waves, each wave owns a 256-element chunk.
// perm[pos] = b in group-major, b-ascending order; gstart/gcnt per group.
// ---------------------------------------------------------------------------
__global__ __launch_bounds__(1024) void sort_kernel(
        const int* __restrict__ targets,
        int* __restrict__ perm,
        int* __restrict__ gstart,
        int* __restrict__ gcnt) {
    __shared__ int cnt[16][P_N];     // per-chunk histograms
    __shared__ int offs[16][P_N];    // scatter base per chunk per group
    __shared__ int gbuf[B_N];        // cached group ids
    __shared__ int total[P_N];
    __shared__ int sc[P_N];

    const int tid  = threadIdx.x;
    const int wave = tid >> 6;
    const int lane = tid & 63;

    for (int i = tid; i < 16 * P_N; i += 1024) ((int*)cnt)[i] = 0;
    __syncthreads();

    // per-chunk histogram (LDS atomics: counts are order-independent -> deterministic)
    for (int e = 0; e < 4; ++e) {
        int b = wave * 256 + e * 64 + lane;
        int g = targets[b];
        gbuf[b] = g;
        atomicAdd(&cnt[wave][g], 1);
    }
    __syncthreads();

    if (tid < P_N) {
        int s = 0;
        for (int w = 0; w < 16; ++w) s += cnt[w][tid];
        total[tid] = s;
        sc[tid] = s;
    }
    __syncthreads();
    // inclusive scan over groups (Hillis-Steele)
    for (int off = 1; off < P_N; off <<= 1) {
        int v = 0;
        if (tid < P_N && tid >= off) v = sc[tid - off];
        __syncthreads();
        if (tid < P_N) sc[tid] += v;
        __syncthreads();
    }
    if (tid < P_N) {
        int st = sc[tid] - total[tid];      // exclusive
        gstart[tid] = st;
        gcnt[tid]   = total[tid];
        int run = st;
        for (int w = 0; w < 16; ++w) { offs[w][tid] = run; run += cnt[w][tid]; }
    }
    __syncthreads();

    // deterministic intra-chunk rank + scatter
    for (int e = 0; e < 4; ++e) {
        int b = wave * 256 + e * 64 + lane;
        int g = gbuf[b];
        int r = 0;
        for (int j = wave * 256; j < b; ++j) r += (gbuf[j] == g) ? 1 : 0;
        perm[offs[wave][g] + r] = b;
    }
}

// ---------------------------------------------------------------------------
// Kernel 2: gather rows in sorted order + expmap0; wave per output row.
// ---------------------------------------------------------------------------
__global__ __launch_bounds__(256) void gather_expmap_kernel(
        const float* __restrict__ reps,
        const int*   __restrict__ perm,
        float* __restrict__ xs,
        float* __restrict__ x2s) {
    int pos  = blockIdx.x * 4 + (threadIdx.x >> 6);
    int lane = threadIdx.x & 63;
    int b = perm[pos];
    float2 v = ((const float2*)(reps + (size_t)b * D_N))[lane];
    float n2 = wred64(v.x * v.x + v.y * v.y);
    float nn = fmaxf(sqrtf(n2), EPSF);
    float s  = tanhf(nn) / nn;
    float2 o; o.x = v.x * s; o.y = v.y * s;
    ((float2*)(xs + (size_t)pos * D_N))[lane] = o;
    if (lane == 0) x2s[pos] = n2 * s * s;   // ||o||^2 exactly
}

// ---------------------------------------------------------------------------
// Kernel 3: Karcher mean per group, ONE WAVE per block, no per-member shuffles.
// mdiff = (sum_b w_b x_b)/cnt - (sum_b cb_b inv_b)/cnt * mu, w_b scalar.
// ---------------------------------------------------------------------------
__global__ __launch_bounds__(64) void proto_kernel(
        const float* __restrict__ xs,
        const float* __restrict__ x2s,
        const int*   __restrict__ gstart,
        const int*   __restrict__ gcnt,
        float* __restrict__ mu_out,
        float* __restrict__ mu2_out) {
    __shared__ float mu_lds[D_N];
    __shared__ float w_lds[B_N];

    const int p    = blockIdx.x;
    const int lane = threadIdx.x;
    const int s0   = gstart[p];
    const int n    = gcnt[p];

    float2 mu; mu.x = 0.f; mu.y = 0.f;
    float mu2 = 0.f;

    if (n > 0) {
        const float inv_cnt = 1.0f / (float)n;

        // init: Euclidean mean, lane = dim (float2), coalesced contiguous rows
        float2 acc; acc.x = 0.f; acc.y = 0.f;
        for (int t = 0; t < n; ++t) {
            float2 v = ((const float2*)(xs + (size_t)(s0 + t) * D_N))[lane];
            acc.x += v.x; acc.y += v.y;
        }
        mu.x = acc.x * inv_cnt; mu.y = acc.y * inv_cnt;
        float m2   = wred64(mu.x * mu.x + mu.y * mu.y);
        float norm = fmaxf(sqrtf(m2), EPSF);
        float fac  = fminf(1.0f, MAXNORM / norm);
        mu.x *= fac; mu.y *= fac;
        mu2 = m2 * fac * fac;
        mu_lds[2 * lane]     = mu.x;
        mu_lds[2 * lane + 1] = mu.y;
        __syncthreads();

        for (int it = 0; it < ITERS; ++it) {
            // ---- phase 1: lane = member; dots via d-loop, no shuffles
            float scb = 0.f;
            for (int base = 0; base < n; base += 64) {
                int  m   = base + lane;
                bool act = (m < n);
                int  ridx = s0 + (act ? m : 0);
                const float4* row = (const float4*)(xs + (size_t)ridx * D_N);
                const float4* mu4 = (const float4*)mu_lds;
                float dot = 0.f;
                #pragma unroll 8
                for (int j = 0; j < D_N / 4; ++j) {
                    float4 a = row[j];
                    float4 b = mu4[j];      // LDS broadcast, conflict-free
                    dot += a.x * b.x + a.y * b.y + a.z * b.z + a.w * b.w;
                }
                float x2v = act ? x2s[s0 + m] : 0.f;
                float ca  = 1.0f - 2.0f * dot + mu2;
                float cb  = 1.0f - x2v;
                float den = 1.0f - 2.0f * dot + x2v * mu2;
                float inv = 1.0f / fmaxf(den, EPSF);
                float wv  = act ? ca * inv : 0.f;
                float cbt = act ? cb * inv : 0.f;
                scb += wred64(cbt);
                w_lds[m] = wv;
            }
            __syncthreads();

            // ---- phase 2: lane = dim; weighted row sum, no shuffles
            float2 md; md.x = 0.f; md.y = 0.f;
            for (int t = 0; t < n; ++t) {
                float  wv = w_lds[t];       // LDS broadcast
                float2 xv = ((const float2*)(xs + (size_t)(s0 + t) * D_N))[lane];
                md.x += wv * xv.x; md.y += wv * xv.y;
            }
            float scs = scb * inv_cnt;
            md.x = md.x * inv_cnt - scs * mu.x;
            md.y = md.y * inv_cnt - scs * mu.y;

            // ---- mu <- project(mobius_add(mu, md)): 3 dependent wred64 chains
            float y2  = wred64(md.x * md.x + md.y * md.y);
            float xy  = wred64(mu.x * md.x + mu.y * md.y);
            float ca  = 1.0f + 2.0f * xy + y2;
            float cb  = 1.0f - mu2;
            float den = 1.0f + 2.0f * xy + mu2 * y2;
            float inv = 1.0f / fmaxf(den, EPSF);
            float2 tv;
            tv.x = (ca * mu.x + cb * md.x) * inv;
            tv.y = (ca * mu.y + cb * md.y) * inv;
            float t2    = wred64(tv.x * tv.x + tv.y * tv.y);
            float norm2 = fmaxf(sqrtf(t2), EPSF);
            float fac2  = fminf(1.0f, MAXNORM / norm2);
            mu.x = tv.x * fac2; mu.y = tv.y * fac2;
            mu2  = t2 * fac2 * fac2;

            __syncthreads();
            mu_lds[2 * lane]     = mu.x;
            mu_lds[2 * lane + 1] = mu.y;
            __syncthreads();
        }
    }

    // final project_to_ball
    {
        float norm = fmaxf(sqrtf(mu2), EPSF);
        float fac  = fminf(1.0f, MAXNORM / norm);
        mu.x *= fac; mu.y *= fac;
        mu2  = mu2 * fac * fac;
    }
    ((float2*)(mu_out + (size_t)p * D_N))[lane] = mu;
    if (lane == 0) mu2_out[p] = mu2;
}

// ---------------------------------------------------------------------------
// Kernel 4: Poincare distance per upper-tri pair (wave per pair); x2 cached.
// ---------------------------------------------------------------------------
__global__ __launch_bounds__(256) void dist_kernel(
        const float* __restrict__ mu,
        const float* __restrict__ mu2s,
        float* __restrict__ dB) {
    int k    = blockIdx.x * 4 + (threadIdx.x >> 6);
    int lane = threadIdx.x & 63;
    if (k >= NPAIRS) return;

    int i = (int)((float)P_N - 0.5f -
                  sqrtf(((float)P_N - 0.5f) * ((float)P_N - 0.5f) - 2.0f * (float)k));
    if (i < 0) i = 0;
    while ((i + 1) * (2 * P_N - i - 2) / 2 <= k) ++i;
    while (i * (2 * P_N - i - 1) / 2 > k) --i;
    int j = k - i * (2 * P_N - i - 1) / 2 + i + 1;

    float2 a = ((const float2*)(mu + (size_t)i * D_N))[lane];
    float2 b = ((const float2*)(mu + (size_t)j * D_N))[lane];
    float dx = a.x - b.x, dy = a.y - b.y;
    float d2 = wred64(dx * dx + dy * dy);
    float ai = fmaxf(1.0f - mu2s[i], EPSF);
    float aj = fmaxf(1.0f - mu2s[j], EPSF);
    float z  = 1.0f + 2.0f * d2 / fmaxf(ai * aj, EPSF);
    z = fmaxf(z, 1.0f + EPSF);
    if (lane == 0) dB[k] = acoshf(z);
}

// ---------------------------------------------------------------------------
// Kernel 5: Pearson correlation, single block.
// ---------------------------------------------------------------------------
__global__ __launch_bounds__(256) void corr_kernel(
        const float* __restrict__ dB,
        const int*   __restrict__ dT,
        float* __restrict__ out) {
    __shared__ double sh[4][5];
    const int tid  = threadIdx.x;
    const int wave = tid >> 6;
    const int lane = tid & 63;

    double s1 = 0.0, s2 = 0.0, st = 0.0, st2 = 0.0, sbt = 0.0;
    for (int k = tid; k < NPAIRS; k += 256) {
        double b = (double)dB[k];
        double t = (double)dT[k];
        s1 += b; s2 += b * b; st += t; st2 += t * t; sbt += b * t;
    }
    s1  = wred64d(s1);
    s2  = wred64d(s2);
    st  = wred64d(st);
    st2 = wred64d(st2);
    sbt = wred64d(sbt);
    if (lane == 0) {
        sh[wave][0] = s1; sh[wave][1] = s2; sh[wave][2] = st;
        sh[wave][3] = st2; sh[wave][4] = sbt;
    }
    __syncthreads();
    if (tid == 0) {
        double t1 = 0, t2 = 0, t3 = 0, t4 = 0, t5 = 0;
        for (int w = 0; w < 4; ++w) {
            t1 += sh[w][0]; t2 += sh[w][1]; t3 += sh[w][2];
            t4 += sh[w][3]; t5 += sh[w][4];
        }
        const double nn = (double)NPAIRS;
        double mb  = t1 / nn;
        double mt  = t3 / nn;
        double cov = t5 - nn * mb * mt;
        double vb  = t2 - nn * mb * mb;
        double vt  = t4 - nn * mt * mt;
        double corr = cov / sqrt(vb * vt);
        double res  = isnan(corr) ? 1.0 : (1.0 - corr);
        out[0] = (float)res;
    }
}

// ---------------------------------------------------------------------------
extern "C" void kernel_launch(void* const* d_in, const int* in_sizes, int n_in,
                              void* d_out, int out_size, void* d_ws, size_t ws_size,
                              hipStream_t stream) {
    const float* reps    = (const float*)d_in[0];
    const int*   targets = (const int*)d_in[1];
    const int*   dT      = (const int*)d_in[2];
    float* out = (float*)d_out;

    float* xs     = (float*)d_ws;              // B*D    = 524288 f
    float* x2s    = xs   + (size_t)B_N * D_N;  // B      =   4096 f
    float* mu     = x2s  + B_N;                // P*D    =  16384 f
    float* mu2s   = mu   + (size_t)P_N * D_N;  // P      =    128 f
    float* dB     = mu2s + P_N;                // NPAIRS =   8128 f
    int*   perm   = (int*)(dB + NPAIRS);       // B      =   4096 i
    int*   gstart = perm + B_N;                // P
    int*   gcnt   = gstart + P_N;              // P      -> ~2.2 MB total

    sort_kernel<<<1, 1024, 0, stream>>>(targets, perm, gstart, gcnt);
    gather_expmap_kernel<<<B_N / 4, 256, 0, stream>>>(reps, perm, xs, x2s);
    proto_kernel<<<P_N, 64, 0, stream>>>(xs, x2s, gstart, gcnt, mu, mu2s);
    dist_kernel<<<(NPAIRS + 3) / 4, 256, 0, stream>>>(mu, mu2s, dB);
    corr_kernel<<<1, 256, 0, stream>>>(dB, dT, out);
}

// Round 3
// 78.329 us; speedup vs baseline: 1.1537x; 1.1256x over previous
//
#include <hip/hip_runtime.h>
#include <math.h>

#define EPSF    1e-6f
#define B_N     4096
#define D_N     128
#define P_N     128
#define NPAIRS  (P_N * (P_N - 1) / 2)   // 8128
#define ITERS   10
#define MAXNORM 0.99999f                 // (1 - 1e-5) / sqrt(c), c = 1
#define CHUNK   96                       // staged rows per group (n>96 falls back to global)

// ---------------------------------------------------------------------------
// DPP-based wave64 sum reductions (~50cy vs ~720cy for ds_swizzle shuffles).
// Result broadcast to all lanes via readlane(63).
// ---------------------------------------------------------------------------
__device__ __forceinline__ float wsum64(float x) {
    float t;
    t = __int_as_float(__builtin_amdgcn_update_dpp(0, __float_as_int(x), 0x111, 0xf, 0xf, true)); x += t; // row_shr:1
    t = __int_as_float(__builtin_amdgcn_update_dpp(0, __float_as_int(x), 0x112, 0xf, 0xf, true)); x += t; // row_shr:2
    t = __int_as_float(__builtin_amdgcn_update_dpp(0, __float_as_int(x), 0x114, 0xf, 0xf, true)); x += t; // row_shr:4
    t = __int_as_float(__builtin_amdgcn_update_dpp(0, __float_as_int(x), 0x118, 0xf, 0xf, true)); x += t; // row_shr:8
    t = __int_as_float(__builtin_amdgcn_update_dpp(0, __float_as_int(x), 0x142, 0xf, 0xf, true)); x += t; // row_bcast:15
    t = __int_as_float(__builtin_amdgcn_update_dpp(0, __float_as_int(x), 0x143, 0xf, 0xf, true)); x += t; // row_bcast:31
    return __int_as_float(__builtin_amdgcn_readlane(__float_as_int(x), 63));
}

__device__ __forceinline__ void wsum64_2(float& a, float& b) {
    float ta, tb;
#define DPP_STEP(ctrl) \
    ta = __int_as_float(__builtin_amdgcn_update_dpp(0, __float_as_int(a), ctrl, 0xf, 0xf, true)); \
    tb = __int_as_float(__builtin_amdgcn_update_dpp(0, __float_as_int(b), ctrl, 0xf, 0xf, true)); \
    a += ta; b += tb;
    DPP_STEP(0x111) DPP_STEP(0x112) DPP_STEP(0x114) DPP_STEP(0x118) DPP_STEP(0x142) DPP_STEP(0x143)
#undef DPP_STEP
    a = __int_as_float(__builtin_amdgcn_readlane(__float_as_int(a), 63));
    b = __int_as_float(__builtin_amdgcn_readlane(__float_as_int(b), 63));
}

__device__ __forceinline__ double wred64d(double v) {
    v += __shfl_xor(v, 1);
    v += __shfl_xor(v, 2);
    v += __shfl_xor(v, 4);
    v += __shfl_xor(v, 8);
    v += __shfl_xor(v, 16);
    v += __shfl_xor(v, 32);
    return v;
}

// match lanes with equal 7-bit group id via ballots over bits
__device__ __forceinline__ unsigned long long match7(int g) {
    unsigned long long m = ~0ULL;
#pragma unroll
    for (int bit = 0; bit < 7; ++bit) {
        unsigned long long bb = __ballot(((g >> bit) & 1) != 0);
        m &= (((g >> bit) & 1) != 0) ? bb : ~bb;
    }
    return m;
}

// ---------------------------------------------------------------------------
// Kernel 1: deterministic counting sort via ballot-match (no serial scans).
// 512 threads = 8 waves, each wave owns 8 rounds of 64 elements.
// Output perm is group-major, b-ascending. gstart/gcnt per group.
// ---------------------------------------------------------------------------
__global__ __launch_bounds__(512) void sort_kernel(
        const int* __restrict__ targets,
        int* __restrict__ perm,
        int* __restrict__ gstart,
        int* __restrict__ gcnt) {
    __shared__ int cnt[8][P_N];
    __shared__ int offs[8][P_N];
    __shared__ int tot[P_N];
    __shared__ int sc[P_N];
    __shared__ int gcache[B_N];

    const int tid  = threadIdx.x;
    const int wave = tid >> 6;
    const int lane = tid & 63;

    for (int i = tid; i < 8 * P_N; i += 512) ((int*)cnt)[i] = 0;
    __syncthreads();

    const unsigned long long lowmask = (1ULL << lane) - 1ULL;

    // pass 1: histogram (leader per (wave, g, round) -> exclusive LDS address)
#pragma unroll
    for (int r = 0; r < 8; ++r) {
        int b = wave * 512 + r * 64 + lane;
        int g = targets[b];
        gcache[b] = g;
        unsigned long long mk = match7(g);
        int rank = __popcll(mk & lowmask);
        if (rank == 0) cnt[wave][g] += __popcll(mk);
    }
    __syncthreads();

    if (tid < P_N) {
        int s = 0;
#pragma unroll
        for (int w = 0; w < 8; ++w) s += cnt[w][tid];
        tot[tid] = s;
        sc[tid]  = s;
    }
    __syncthreads();
    for (int off = 1; off < P_N; off <<= 1) {
        int v = 0;
        if (tid < P_N && tid >= off) v = sc[tid - off];
        __syncthreads();
        if (tid < P_N) sc[tid] += v;
        __syncthreads();
    }
    if (tid < P_N) {
        int st = sc[tid] - tot[tid];           // exclusive prefix
        gstart[tid] = st;
        gcnt[tid]   = tot[tid];
        int run = st;
#pragma unroll
        for (int w = 0; w < 8; ++w) { offs[w][tid] = run; run += cnt[w][tid]; }
    }
    __syncthreads();

    // pass 2: scatter (rounds in order within wave -> deterministic, b-ascending)
#pragma unroll
    for (int r = 0; r < 8; ++r) {
        int b = wave * 512 + r * 64 + lane;
        int g = gcache[b];
        unsigned long long mk = match7(g);
        int rank = __popcll(mk & lowmask);
        int base = offs[wave][g];              // read by all same-g lanes
        perm[base + rank] = b;
        if (rank == 0) offs[wave][g] = base + __popcll(mk);  // leader bump
    }
}

// ---------------------------------------------------------------------------
// Kernel 2: Karcher mean per group, 1 wave/block. expmap fused (scale s_b
// folded into weights), rows LDS-staged once (XOR-swizzled), DPP reductions,
// analytic |t|^2 (no third reduction chain).
// ---------------------------------------------------------------------------
__global__ __launch_bounds__(64) void proto_kernel(
        const float* __restrict__ reps,
        const int*   __restrict__ perm,
        const int*   __restrict__ gstart,
        const int*   __restrict__ gcnt,
        float* __restrict__ mu_out,
        float* __restrict__ mu2_out) {
    __shared__ float4 Xs[CHUNK * 32];      // 49152 B, row m block j at [m*32 + (j ^ (m&7))]
    __shared__ float  s_sc[CHUNK];
    __shared__ float  s_x2[CHUNK];
    __shared__ float  w_lds[CHUNK];
    __shared__ float  cbt_lds[CHUNK];
    __shared__ float  mu_lds[D_N];

    const int p    = blockIdx.x;
    const int lane = threadIdx.x;
    const int s0   = gstart[p];
    const int n    = gcnt[p];
    const int nst  = (n < CHUNK) ? n : CHUNK;
    const float4* reps4 = (const float4*)reps;

    // ---- stage rows (raw reps) into LDS, swizzled
    for (int idx = lane; idx < nst * 32; idx += 64) {
        int m = idx >> 5, j = idx & 31;
        int b = perm[s0 + m];
        Xs[m * 32 + (j ^ (m & 7))] = reps4[(size_t)b * 32 + j];
    }
    __syncthreads();

    // ---- per-staged-member expmap scale: s = tanh(|x|)/|x|, x2p = |s*x|^2
    for (int m0 = 0; m0 < nst; m0 += 64) {
        int m = m0 + lane;
        if (m < nst) {
            float n2 = 0.f;
#pragma unroll 8
            for (int j = 0; j < 32; ++j) {
                float4 a = Xs[m * 32 + (j ^ (m & 7))];
                n2 += a.x * a.x + a.y * a.y + a.z * a.z + a.w * a.w;
            }
            float nn = fmaxf(sqrtf(n2), EPSF);
            float sv = tanhf(nn) / nn;
            s_sc[m] = sv;
            s_x2[m] = n2 * sv * sv;
        }
    }
    __syncthreads();

    float2 mu  = make_float2(0.f, 0.f);
    float  mu2 = 0.f;

    if (n > 0) {
        const float inv_cnt = 1.0f / (float)n;

        // ---- init: Euclidean mean of expmapped points
        float2 S = make_float2(0.f, 0.f);
        for (int c0 = 0; c0 < n; c0 += CHUNK) {
            int clen = (n - c0 < CHUNK) ? (n - c0) : CHUNK;
            for (int m0 = 0; m0 < clen; m0 += 64) {
                int m = m0 + lane;
                if (m < clen) {
                    int gm = c0 + m;
                    if (gm < nst) {
                        w_lds[m] = s_sc[gm];
                    } else {
                        int b = perm[s0 + gm];
                        float n2 = 0.f;
#pragma unroll 8
                        for (int j = 0; j < 32; ++j) {
                            float4 a = reps4[(size_t)b * 32 + j];
                            n2 += a.x * a.x + a.y * a.y + a.z * a.z + a.w * a.w;
                        }
                        float nn = fmaxf(sqrtf(n2), EPSF);
                        w_lds[m] = tanhf(nn) / nn;
                    }
                }
            }
            __syncthreads();
#pragma unroll 4
            for (int t = 0; t < clen; ++t) {
                int gm = c0 + t;
                float wv = w_lds[t];
                float2 xv;
                if (gm < nst) {
                    int j = lane >> 1, jj = j ^ (gm & 7);
                    xv = *(const float2*)((const float*)&Xs[gm * 32 + jj] + (lane & 1) * 2);
                } else {
                    int b = perm[s0 + gm];
                    xv = ((const float2*)(reps + (size_t)b * D_N))[lane];
                }
                S.x += wv * xv.x; S.y += wv * xv.y;
            }
            __syncthreads();
        }
        mu.x = S.x * inv_cnt; mu.y = S.y * inv_cnt;
        float m2   = wsum64(mu.x * mu.x + mu.y * mu.y);
        float norm = fmaxf(sqrtf(m2), EPSF);
        float fac  = fminf(1.0f, MAXNORM / norm);
        mu.x *= fac; mu.y *= fac;
        mu2 = m2 * fac * fac;
        ((float2*)mu_lds)[lane] = mu;
        __syncthreads();

        // ---- Karcher iterations
        for (int it = 0; it < ITERS; ++it) {
            float2 S2  = make_float2(0.f, 0.f);
            float  scb = 0.f;
            for (int c0 = 0; c0 < n; c0 += CHUNK) {
                int clen = (n - c0 < CHUNK) ? (n - c0) : CHUNK;
                // phase 1: lane = member; per-member scalars -> LDS (no reduction)
                for (int m0 = 0; m0 < clen; m0 += 64) {
                    int m = m0 + lane;
                    if (m < clen) {
                        int gm = c0 + m;
                        const float4* mu4 = (const float4*)mu_lds;
                        float dotr = 0.f, sc_m, x2_m;
                        if (gm < nst) {
#pragma unroll 8
                            for (int j = 0; j < 32; ++j) {
                                float4 a = Xs[gm * 32 + (j ^ (gm & 7))];
                                float4 q = mu4[j];
                                dotr += a.x * q.x + a.y * q.y + a.z * q.z + a.w * q.w;
                            }
                            sc_m = s_sc[gm]; x2_m = s_x2[gm];
                        } else {
                            int b = perm[s0 + gm];
                            float n2 = 0.f;
#pragma unroll 8
                            for (int j = 0; j < 32; ++j) {
                                float4 a = reps4[(size_t)b * 32 + j];
                                float4 q = mu4[j];
                                dotr += a.x * q.x + a.y * q.y + a.z * q.z + a.w * q.w;
                                n2   += a.x * a.x + a.y * a.y + a.z * a.z + a.w * a.w;
                            }
                            float nn = fmaxf(sqrtf(n2), EPSF);
                            sc_m = tanhf(nn) / nn;
                            x2_m = n2 * sc_m * sc_m;
                        }
                        float dot = sc_m * dotr;                 // <xp_b, mu>
                        float ca  = 1.0f - 2.0f * dot + mu2;
                        float cb  = 1.0f - x2_m;
                        float den = fmaxf(1.0f - 2.0f * dot + x2_m * mu2, EPSF);
                        float inv = 1.0f / den;
                        w_lds[m]   = ca * inv * sc_m;            // weight on RAW row
                        cbt_lds[m] = cb * inv;                   // coef on mu
                    }
                }
                __syncthreads();
                // phase 2: lane = dim; weighted row sum + redundant scalar sum
#pragma unroll 4
                for (int t = 0; t < clen; ++t) {
                    int gm = c0 + t;
                    float wv = w_lds[t], cv = cbt_lds[t];
                    float2 xv;
                    if (gm < nst) {
                        int j = lane >> 1, jj = j ^ (gm & 7);
                        xv = *(const float2*)((const float*)&Xs[gm * 32 + jj] + (lane & 1) * 2);
                    } else {
                        int b = perm[s0 + gm];
                        xv = ((const float2*)(reps + (size_t)b * D_N))[lane];
                    }
                    S2.x += wv * xv.x; S2.y += wv * xv.y;
                    scb  += cv;
                }
                __syncthreads();
            }
            float scs = scb * inv_cnt;
            float2 md;
            md.x = S2.x * inv_cnt - scs * mu.x;
            md.y = S2.y * inv_cnt - scs * mu.y;

            // mu <- project(mobius_add(mu, md)); |t|^2 analytic
            float a0 = md.x * md.x + md.y * md.y;   // -> y2
            float a1 = mu.x * md.x + mu.y * md.y;   // -> xy
            wsum64_2(a0, a1);
            float ca  = 1.0f + 2.0f * a1 + a0;
            float cb  = 1.0f - mu2;
            float den = fmaxf(1.0f + 2.0f * a1 + mu2 * a0, EPSF);
            float inv = 1.0f / den;
            float2 tv;
            tv.x = (ca * mu.x + cb * md.x) * inv;
            tv.y = (ca * mu.y + cb * md.y) * inv;
            float t2  = (ca * ca * mu2 + 2.0f * ca * cb * a1 + cb * cb * a0) * inv * inv;
            float nrm = fmaxf(sqrtf(t2), EPSF);
            float fc  = fminf(1.0f, MAXNORM / nrm);
            mu.x = tv.x * fc; mu.y = tv.y * fc;
            mu2  = t2 * fc * fc;
            ((float2*)mu_lds)[lane] = mu;
            __syncthreads();
        }
    }

    // final project_to_ball
    {
        float nrm = fmaxf(sqrtf(mu2), EPSF);
        float fc  = fminf(1.0f, MAXNORM / nrm);
        mu.x *= fc; mu.y *= fc;
        mu2  = mu2 * fc * fc;
    }
    ((float2*)(mu_out + (size_t)p * D_N))[lane] = mu;
    if (lane == 0) mu2_out[p] = mu2;
}

// ---------------------------------------------------------------------------
// Kernel 3: Poincare distance per upper-tri pair (wave per pair), DPP reduce.
// ---------------------------------------------------------------------------
__global__ __launch_bounds__(256) void dist_kernel(
        const float* __restrict__ mu,
        const float* __restrict__ mu2s,
        float* __restrict__ dB) {
    int k    = blockIdx.x * 4 + (threadIdx.x >> 6);
    int lane = threadIdx.x & 63;
    if (k >= NPAIRS) return;

    int i = (int)((float)P_N - 0.5f -
                  sqrtf(((float)P_N - 0.5f) * ((float)P_N - 0.5f) - 2.0f * (float)k));
    if (i < 0) i = 0;
    while ((i + 1) * (2 * P_N - i - 2) / 2 <= k) ++i;
    while (i * (2 * P_N - i - 1) / 2 > k) --i;
    int j = k - i * (2 * P_N - i - 1) / 2 + i + 1;

    float2 a = ((const float2*)(mu + (size_t)i * D_N))[lane];
    float2 b = ((const float2*)(mu + (size_t)j * D_N))[lane];
    float dx = a.x - b.x, dy = a.y - b.y;
    float d2 = wsum64(dx * dx + dy * dy);
    float ai = fmaxf(1.0f - mu2s[i], EPSF);
    float aj = fmaxf(1.0f - mu2s[j], EPSF);
    float z  = 1.0f + 2.0f * d2 / fmaxf(ai * aj, EPSF);
    z = fmaxf(z, 1.0f + EPSF);
    if (lane == 0) dB[k] = acoshf(z);
}

// ---------------------------------------------------------------------------
// Kernel 4: Pearson correlation, single block.
// ---------------------------------------------------------------------------
__global__ __launch_bounds__(256) void corr_kernel(
        const float* __restrict__ dB,
        const int*   __restrict__ dT,
        float* __restrict__ out) {
    __shared__ double sh[4][5];
    const int tid  = threadIdx.x;
    const int wave = tid >> 6;
    const int lane = tid & 63;

    double s1 = 0.0, s2 = 0.0, st = 0.0, st2 = 0.0, sbt = 0.0;
    for (int k = tid; k < NPAIRS; k += 256) {
        double b = (double)dB[k];
        double t = (double)dT[k];
        s1 += b; s2 += b * b; st += t; st2 += t * t; sbt += b * t;
    }
    s1  = wred64d(s1);
    s2  = wred64d(s2);
    st  = wred64d(st);
    st2 = wred64d(st2);
    sbt = wred64d(sbt);
    if (lane == 0) {
        sh[wave][0] = s1; sh[wave][1] = s2; sh[wave][2] = st;
        sh[wave][3] = st2; sh[wave][4] = sbt;
    }
    __syncthreads();
    if (tid == 0) {
        double t1 = 0, t2 = 0, t3 = 0, t4 = 0, t5 = 0;
        for (int w = 0; w < 4; ++w) {
            t1 += sh[w][0]; t2 += sh[w][1]; t3 += sh[w][2];
            t4 += sh[w][3]; t5 += sh[w][4];
        }
        const double nn = (double)NPAIRS;
        double mb  = t1 / nn;
        double mt  = t3 / nn;
        double cov = t5 - nn * mb * mt;
        double vb  = t2 - nn * mb * mb;
        double vt  = t4 - nn * mt * mt;
        double corr = cov / sqrt(vb * vt);
        double res  = isnan(corr) ? 1.0 : (1.0 - corr);
        out[0] = (float)res;
    }
}

// ---------------------------------------------------------------------------
extern "C" void kernel_launch(void* const* d_in, const int* in_sizes, int n_in,
                              void* d_out, int out_size, void* d_ws, size_t ws_size,
                              hipStream_t stream) {
    const float* reps    = (const float*)d_in[0];
    const int*   targets = (const int*)d_in[1];
    const int*   dT      = (const int*)d_in[2];
    float* out = (float*)d_out;

    float* mu     = (float*)d_ws;                 // P*D    = 16384 f
    float* mu2s   = mu + (size_t)P_N * D_N;       // P      =   128 f
    float* dB     = mu2s + P_N;                   // NPAIRS =  8128 f
    int*   perm   = (int*)(dB + NPAIRS);          // B      =  4096 i
    int*   gstart = perm + B_N;                   // P
    int*   gcnt   = gstart + P_N;                 // P      -> ~120 KB total

    sort_kernel<<<1, 512, 0, stream>>>(targets, perm, gstart, gcnt);
    proto_kernel<<<P_N, 64, 0, stream>>>(reps, perm, gstart, gcnt, mu, mu2s);
    dist_kernel<<<(NPAIRS + 3) / 4, 256, 0, stream>>>(mu, mu2s, dB);
    corr_kernel<<<1, 256, 0, stream>>>(dB, dT, out);
}

// Round 5
// 72.761 us; speedup vs baseline: 1.2420x; 1.0765x over previous
//
#include <hip/hip_runtime.h>
#include <math.h>

#define EPSF    1e-6f
#define B_N     4096
#define P_N     128
#define D_N     128
#define NPAIRS  (P_N * (P_N - 1) / 2)   // 8128
#define ITERS   10
#define MAXNORM 0.99999f                 // (1 - 1e-5) / sqrt(c), c = 1
#define MCAP    512                      // max members per group handled
#define WCAP    128                      // per-wave member list capacity

// ---------------------------------------------------------------------------
// DPP helpers (ctrl must be a compile-time constant -> template parameter)
// ---------------------------------------------------------------------------
template <int CTRL>
__device__ __forceinline__ float dppadd(float x) {
    float t = __int_as_float(__builtin_amdgcn_update_dpp(
        0, __float_as_int(x), CTRL, 0xf, 0xf, true));
    return x + t;
}
// sum over aligned groups of 8 lanes (result in every lane of the group)
__device__ __forceinline__ float red8(float x) {
    x = dppadd<0xB1>(x);    // quad_perm [1,0,3,2]  : xor 1
    x = dppadd<0x4E>(x);    // quad_perm [2,3,0,1]  : xor 2
    x = dppadd<0x141>(x);   // row_half_mirror      : xor 7 (combines quads)
    return x;
}
// full wave64 sum, broadcast via readlane(63)
__device__ __forceinline__ float wsum64(float x) {
    x = dppadd<0x111>(x); x = dppadd<0x112>(x); x = dppadd<0x114>(x);
    x = dppadd<0x118>(x); x = dppadd<0x142>(x); x = dppadd<0x143>(x);
    return __int_as_float(__builtin_amdgcn_readlane(__float_as_int(x), 63));
}
__device__ __forceinline__ void wsum64_2(float& a, float& b) {
#define DPP_STEP(ctrl) \
    a = dppadd<ctrl>(a); b = dppadd<ctrl>(b);
    DPP_STEP(0x111) DPP_STEP(0x112) DPP_STEP(0x114) DPP_STEP(0x118) DPP_STEP(0x142) DPP_STEP(0x143)
#undef DPP_STEP
    a = __int_as_float(__builtin_amdgcn_readlane(__float_as_int(a), 63));
    b = __int_as_float(__builtin_amdgcn_readlane(__float_as_int(b), 63));
}
__device__ __forceinline__ double wred64d(double v) {
    v += __shfl_xor(v, 1);  v += __shfl_xor(v, 2);  v += __shfl_xor(v, 4);
    v += __shfl_xor(v, 8);  v += __shfl_xor(v, 16); v += __shfl_xor(v, 32);
    return v;
}

__device__ __forceinline__ float dot16(const float4* r, const float4* m) {
    float d = 0.f;
#pragma unroll
    for (int j = 0; j < 4; ++j)
        d += r[j].x * m[j].x + r[j].y * m[j].y + r[j].z * m[j].z + r[j].w * m[j].w;
    return d;
}

// ---------------------------------------------------------------------------
// Kernel 1: per-group Karcher mean. 256 threads = 32 member-slots x 8 dim-octs.
// Membership found by in-block ballot scan; rows expmapped into registers
// (tiles 0,1 = 64 members) + LDS copy for the dim-layout phase; weights
// per-member computed redundantly (no broadcast); 3 barriers / iteration.
// ---------------------------------------------------------------------------
__global__ __launch_bounds__(256) void proto_kernel(
        const float* __restrict__ reps,
        const int*   __restrict__ targets,
        float* __restrict__ mu_out,
        float* __restrict__ mu2_out,
        int*   __restrict__ counter) {
    __shared__ int   wtmp[4][WCAP];
    __shared__ int   wcnt[4];
    __shared__ int   woff[4];
    __shared__ int   mlist[MCAP];
    __shared__ int   s_n;
    __shared__ float xs[64 * D_N];       // expmapped rows, tiles 0/1 (32 KiB)
    __shared__ float sc_l[MCAP];         // expmap scale, extra tiles only
    __shared__ float x2_l[MCAP];         // |xp|^2, extra tiles only
    __shared__ float w_l[MCAP];
    __shared__ float cb_l[MCAP];
    __shared__ float mu_lds[D_N];
    __shared__ float part[4][D_N];
    __shared__ float scbp[4];

    const int p    = blockIdx.x;
    const int tid  = threadIdx.x;
    const int wv   = tid >> 6;
    const int lane = tid & 63;
    const int mloc = tid >> 3;           // member slot 0..31
    const int q    = tid & 7;            // dim oct: dims [16q, 16q+16)

    if (p == 0 && tid == 0) counter[0] = 0;   // for distcorr last-block

    // ---- membership scan: wave wv scans targets[wv*1024 .. +1024)
    {
        const unsigned long long lowmask = (1ULL << lane) - 1ULL;
        int cnt = 0;
        for (int r = 0; r < 16; ++r) {
            int b = (wv << 10) + (r << 6) + lane;
            bool mm = (targets[b] == p);
            unsigned long long mk = __ballot(mm);
            if (mm) {
                int pos = cnt + __popcll(mk & lowmask);
                if (pos < WCAP) wtmp[wv][pos] = b;
            }
            cnt += __popcll(mk);
        }
        if (cnt > WCAP) cnt = WCAP;
        if (lane == 0) wcnt[wv] = cnt;
    }
    __syncthreads();
    if (tid == 0) {
        int c0 = wcnt[0], c1 = wcnt[1], c2 = wcnt[2], c3 = wcnt[3];
        woff[0] = 0; woff[1] = c0; woff[2] = c0 + c1; woff[3] = c0 + c1 + c2;
        int nn = c0 + c1 + c2 + c3;
        s_n = (nn > MCAP) ? MCAP : nn;
    }
    __syncthreads();
    {
        int base = woff[wv], cnt = wcnt[wv];
        for (int i = lane; i < cnt; i += 64) mlist[base + i] = wtmp[wv][i];
    }
    __syncthreads();

    const int   n       = s_n;
    const float inv_cnt = 1.0f / fmaxf((float)n, 1.0f);
    const int   NT      = (n + 31) >> 5;
    const float4* reps4 = (const float4*)reps;

    // ---- register tiles 0,1: load raw, expmap in place, stage to xs
    float4 r0[4], r1[4];
    float  x2_0 = 0.f, x2_1 = 0.f;
    const bool a0 = (mloc < n);
    const bool a1 = (mloc + 32 < n);
    {
        int b0 = a0 ? mlist[mloc] : 0;
#pragma unroll
        for (int j = 0; j < 4; ++j) r0[j] = reps4[(size_t)b0 * 32 + q * 4 + j];
        float ss = 0.f;
#pragma unroll
        for (int j = 0; j < 4; ++j)
            ss += r0[j].x * r0[j].x + r0[j].y * r0[j].y + r0[j].z * r0[j].z + r0[j].w * r0[j].w;
        ss = red8(ss);
        float nn = fmaxf(sqrtf(ss), EPSF);
        float sv = tanhf(nn) / nn;
#pragma unroll
        for (int j = 0; j < 4; ++j) { r0[j].x *= sv; r0[j].y *= sv; r0[j].z *= sv; r0[j].w *= sv; }
        x2_0 = ss * sv * sv;
        if (a0) {
#pragma unroll
            for (int j = 0; j < 4; ++j)
                *(float4*)&xs[mloc * D_N + q * 16 + j * 4] = r0[j];
        }
    }
    {
        int b1 = a1 ? mlist[mloc + 32] : 0;
#pragma unroll
        for (int j = 0; j < 4; ++j) r1[j] = reps4[(size_t)b1 * 32 + q * 4 + j];
        float ss = 0.f;
#pragma unroll
        for (int j = 0; j < 4; ++j)
            ss += r1[j].x * r1[j].x + r1[j].y * r1[j].y + r1[j].z * r1[j].z + r1[j].w * r1[j].w;
        ss = red8(ss);
        float nn = fmaxf(sqrtf(ss), EPSF);
        float sv = tanhf(nn) / nn;
#pragma unroll
        for (int j = 0; j < 4; ++j) { r1[j].x *= sv; r1[j].y *= sv; r1[j].z *= sv; r1[j].w *= sv; }
        x2_1 = ss * sv * sv;
        if (a1) {
#pragma unroll
            for (int j = 0; j < 4; ++j)
                *(float4*)&xs[(mloc + 32) * D_N + q * 16 + j * 4] = r1[j];
        }
    }
    // extra tiles (rare): precompute sc, x2
    for (int ti = 2; ti < NT; ++ti) {
        int  me = ti * 32 + mloc;
        bool ae = (me < n);
        int  b  = ae ? mlist[me] : 0;
        float ss = 0.f;
#pragma unroll
        for (int j = 0; j < 4; ++j) {
            float4 t4 = reps4[(size_t)b * 32 + q * 4 + j];
            ss += t4.x * t4.x + t4.y * t4.y + t4.z * t4.z + t4.w * t4.w;
        }
        ss = red8(ss);
        if (ae && q == 0) {
            float nn = fmaxf(sqrtf(ss), EPSF);
            float sv = tanhf(nn) / nn;
            sc_l[me] = sv;
            x2_l[me] = ss * sv * sv;
        }
    }
    __syncthreads();

    // ---- init: Euclidean mean of expmapped rows (member-parallel, lane=dim)
    float2 S; S.x = 0.f; S.y = 0.f;
    for (int ti = 0; ti < NT; ++ti) {
        for (int k = 0; k < 8; ++k) {
            int m = ti * 32 + wv * 8 + k;
            if (m < n) {
                float2 xv;
                if (ti < 2) {
                    xv = *(const float2*)&xs[m * D_N + 2 * lane];
                } else {
                    int b = mlist[m];
                    float2 rv = ((const float2*)reps)[(size_t)b * 64 + lane];
                    float s = sc_l[m];
                    xv.x = rv.x * s; xv.y = rv.y * s;
                }
                S.x += xv.x; S.y += xv.y;
            }
        }
    }
    *(float2*)&part[wv][2 * lane] = S;
    __syncthreads();
    float2 muf; muf.x = 0.f; muf.y = 0.f;
#pragma unroll
    for (int w2 = 0; w2 < 4; ++w2) {
        float2 pv = *(const float2*)&part[w2][2 * lane];
        muf.x += pv.x; muf.y += pv.y;
    }
    muf.x *= inv_cnt; muf.y *= inv_cnt;
    float m2   = wsum64(muf.x * muf.x + muf.y * muf.y);
    float nrm  = fmaxf(sqrtf(m2), EPSF);
    float fac  = fminf(1.0f, MAXNORM / nrm);
    muf.x *= fac; muf.y *= fac;
    float mu2 = m2 * fac * fac;
    if (wv == 0) *(float2*)&mu_lds[2 * lane] = muf;
    __syncthreads();

    // ---- Karcher iterations
    for (int it = 0; it < ITERS; ++it) {
        // phase 1: member-slot layout, dots from registers + mu_lds slice
        float4 ms[4];
        {
            const float4* mu4 = (const float4*)mu_lds;
#pragma unroll
            for (int j = 0; j < 4; ++j) ms[j] = mu4[q * 4 + j];
        }
        {
            float d = red8(dot16(r0, ms));
            float ca  = 1.0f - 2.0f * d + mu2;
            float cbv = 1.0f - x2_0;
            float den = fmaxf(1.0f - 2.0f * d + x2_0 * mu2, EPSF);
            float iv  = 1.0f / den;
            if (a0 && q == 0) { w_l[mloc] = ca * iv; cb_l[mloc] = cbv * iv; }
        }
        {
            float d = red8(dot16(r1, ms));
            float ca  = 1.0f - 2.0f * d + mu2;
            float cbv = 1.0f - x2_1;
            float den = fmaxf(1.0f - 2.0f * d + x2_1 * mu2, EPSF);
            float iv  = 1.0f / den;
            if (a1 && q == 0) { w_l[mloc + 32] = ca * iv; cb_l[mloc + 32] = cbv * iv; }
        }
        for (int ti = 2; ti < NT; ++ti) {
            int  me = ti * 32 + mloc;
            bool ae = (me < n);
            int  b  = ae ? mlist[me] : 0;
            float d = 0.f;
#pragma unroll
            for (int j = 0; j < 4; ++j) {
                float4 t4 = reps4[(size_t)b * 32 + q * 4 + j];
                d += t4.x * ms[j].x + t4.y * ms[j].y + t4.z * ms[j].z + t4.w * ms[j].w;
            }
            d = red8(d);
            if (ae) {
                float sv  = sc_l[me];
                float x2v = x2_l[me];
                float dp  = sv * d;
                float ca  = 1.0f - 2.0f * dp + mu2;
                float cbv = 1.0f - x2v;
                float den = fmaxf(1.0f - 2.0f * dp + x2v * mu2, EPSF);
                float iv  = 1.0f / den;
                if (q == 0) { w_l[me] = ca * iv; cb_l[me] = cbv * iv; }
            }
        }
        __syncthreads();   // B1: w_l/cb_l ready

        // phase c: lane=dim weighted row sum, member-parallel across waves
        float2 S2; S2.x = 0.f; S2.y = 0.f;
        float  scb = 0.f;
        for (int ti = 0; ti < NT; ++ti) {
            for (int k = 0; k < 8; ++k) {
                int m = ti * 32 + wv * 8 + k;
                if (m < n) {
                    float wvv = w_l[m];
                    scb += cb_l[m];
                    if (ti < 2) {
                        float2 xv = *(const float2*)&xs[m * D_N + 2 * lane];
                        S2.x += wvv * xv.x; S2.y += wvv * xv.y;
                    } else {
                        int b = mlist[m];
                        float2 rv = ((const float2*)reps)[(size_t)b * 64 + lane];
                        float we = wvv * sc_l[m];
                        S2.x += we * rv.x; S2.y += we * rv.y;
                    }
                }
            }
        }
        *(float2*)&part[wv][2 * lane] = S2;
        if (lane == 0) scbp[wv] = scb;
        __syncthreads();   // B2: partials ready

        // combine + mobius update (redundant on every wave)
        float2 T; T.x = 0.f; T.y = 0.f;
#pragma unroll
        for (int w2 = 0; w2 < 4; ++w2) {
            float2 pv = *(const float2*)&part[w2][2 * lane];
            T.x += pv.x; T.y += pv.y;
        }
        float scbt = scbp[0] + scbp[1] + scbp[2] + scbp[3];
        float scs  = scbt * inv_cnt;
        float2 md;
        md.x = T.x * inv_cnt - scs * muf.x;
        md.y = T.y * inv_cnt - scs * muf.y;

        float A0 = md.x * md.x + md.y * md.y;     // |md|^2 partial
        float A1 = muf.x * md.x + muf.y * md.y;   // <mu,md> partial
        wsum64_2(A0, A1);
        float ca  = 1.0f + 2.0f * A1 + A0;
        float cbv = 1.0f - mu2;
        float den = fmaxf(1.0f + 2.0f * A1 + mu2 * A0, EPSF);
        float iv  = 1.0f / den;
        float2 tv;
        tv.x = (ca * muf.x + cbv * md.x) * iv;
        tv.y = (ca * muf.y + cbv * md.y) * iv;
        float t2   = (ca * ca * mu2 + 2.0f * ca * cbv * A1 + cbv * cbv * A0) * iv * iv;
        float nrm2 = fmaxf(sqrtf(t2), EPSF);
        float fc   = fminf(1.0f, MAXNORM / nrm2);
        muf.x = tv.x * fc; muf.y = tv.y * fc;
        mu2   = t2 * fc * fc;

        if (wv == 0) *(float2*)&mu_lds[2 * lane] = muf;
        __syncthreads();   // B3: mu_lds fresh for next phase 1
    }

    // final project_to_ball
    {
        float nf = fmaxf(sqrtf(mu2), EPSF);
        float ff = fminf(1.0f, MAXNORM / nf);
        muf.x *= ff; muf.y *= ff;
        mu2 = mu2 * ff * ff;
    }
    if (wv == 0) {
        ((float2*)(mu_out + (size_t)p * D_N))[lane] = muf;
        if (lane == 0) mu2_out[p] = mu2;
    }
}

// ---------------------------------------------------------------------------
// Kernel 2: distances (wave per pair) + last-block Pearson correlation.
// ---------------------------------------------------------------------------
__global__ __launch_bounds__(256) void distcorr_kernel(
        const float* __restrict__ mu,
        const float* __restrict__ mu2s,
        const int*   __restrict__ dT,
        float* __restrict__ dB,
        int*   __restrict__ counter,
        float* __restrict__ out) {
    const int tid  = threadIdx.x;
    const int wv   = tid >> 6;
    const int lane = tid & 63;
    int k = blockIdx.x * 4 + wv;       // grid = NPAIRS/4 exactly

    int i = (int)((float)P_N - 0.5f -
                  sqrtf(((float)P_N - 0.5f) * ((float)P_N - 0.5f) - 2.0f * (float)k));
    if (i < 0) i = 0;
    while ((i + 1) * (2 * P_N - i - 2) / 2 <= k) ++i;
    while (i * (2 * P_N - i - 1) / 2 > k) --i;
    int j = k - i * (2 * P_N - i - 1) / 2 + i + 1;

    float2 a = ((const float2*)(mu + (size_t)i * D_N))[lane];
    float2 b = ((const float2*)(mu + (size_t)j * D_N))[lane];
    float dx = a.x - b.x, dy = a.y - b.y;
    float d2 = wsum64(dx * dx + dy * dy);
    float ai = fmaxf(1.0f - mu2s[i], EPSF);
    float aj = fmaxf(1.0f - mu2s[j], EPSF);
    float z  = 1.0f + 2.0f * d2 / fmaxf(ai * aj, EPSF);
    z = fmaxf(z, 1.0f + EPSF);
    if (lane == 0) dB[k] = acoshf(z);

    // ---- last block does the correlation
    __syncthreads();                   // drains this block's stores (vmcnt 0)
    __shared__ int s_last;
    if (tid == 0) {
        __threadfence();
        int old = atomicAdd(counter, 1);
        s_last = (old == (int)gridDim.x - 1) ? 1 : 0;
    }
    __syncthreads();
    if (!s_last) return;
    __threadfence();

    __shared__ double sh[4][5];
    double s1 = 0.0, s2 = 0.0, st = 0.0, st2 = 0.0, sbt = 0.0;
    for (int e = tid; e < NPAIRS; e += 256) {
        float bf = __hip_atomic_load(&dB[e], __ATOMIC_RELAXED, __HIP_MEMORY_SCOPE_AGENT);
        double bb = (double)bf;
        double tt = (double)dT[e];
        s1 += bb; s2 += bb * bb; st += tt; st2 += tt * tt; sbt += bb * tt;
    }
    s1  = wred64d(s1);
    s2  = wred64d(s2);
    st  = wred64d(st);
    st2 = wred64d(st2);
    sbt = wred64d(sbt);
    if (lane == 0) {
        sh[wv][0] = s1; sh[wv][1] = s2; sh[wv][2] = st;
        sh[wv][3] = st2; sh[wv][4] = sbt;
    }
    __syncthreads();
    if (tid == 0) {
        double t1 = 0, t2 = 0, t3 = 0, t4 = 0, t5 = 0;
        for (int w = 0; w < 4; ++w) {
            t1 += sh[w][0]; t2 += sh[w][1]; t3 += sh[w][2];
            t4 += sh[w][3]; t5 += sh[w][4];
        }
        const double nn = (double)NPAIRS;
        double mb  = t1 / nn;
        double mt  = t3 / nn;
        double cov = t5 - nn * mb * mt;
        double vb  = t2 - nn * mb * mb;
        double vt  = t4 - nn * mt * mt;
        double corr = cov / sqrt(vb * vt);
        double res  = isnan(corr) ? 1.0 : (1.0 - corr);
        out[0] = (float)res;
    }
}

// ---------------------------------------------------------------------------
extern "C" void kernel_launch(void* const* d_in, const int* in_sizes, int n_in,
                              void* d_out, int out_size, void* d_ws, size_t ws_size,
                              hipStream_t stream) {
    const float* reps    = (const float*)d_in[0];
    const int*   targets = (const int*)d_in[1];
    const int*   dT      = (const int*)d_in[2];
    float* out = (float*)d_out;

    float* mu      = (float*)d_ws;                 // P*D    = 16384 f
    float* mu2s    = mu + (size_t)P_N * D_N;       // P
    float* dB      = mu2s + P_N;                   // NPAIRS
    int*   counter = (int*)(dB + NPAIRS);          // 1

    proto_kernel<<<P_N, 256, 0, stream>>>(reps, targets, mu, mu2s, counter);
    distcorr_kernel<<<NPAIRS / 4, 256, 0, stream>>>(mu, mu2s, dT, dB, counter, out);
}

// Round 6
// 38.596 us; speedup vs baseline: 2.3414x; 1.8852x over previous
//
#include <hip/hip_runtime.h>
#include <math.h>

#define EPSF    1e-6f
#define B_N     4096
#define P_N     128
#define D_N     128
#define NPAIRS  (P_N * (P_N - 1) / 2)   // 8128
#define ITERS   10
#define MAXNORM 0.99999f                 // (1 - 1e-5) / sqrt(c), c = 1
#define MCAP    512                      // max members per group handled
#define WCAP    128                      // per-wave member list capacity

// ---------------------------------------------------------------------------
// DPP helpers (ctrl must be a compile-time constant -> template parameter)
// ---------------------------------------------------------------------------
template <int CTRL>
__device__ __forceinline__ float dppadd(float x) {
    float t = __int_as_float(__builtin_amdgcn_update_dpp(
        0, __float_as_int(x), CTRL, 0xf, 0xf, true));
    return x + t;
}
// sum over aligned groups of 8 lanes (result in every lane of the group)
__device__ __forceinline__ float red8(float x) {
    x = dppadd<0xB1>(x);    // quad_perm [1,0,3,2]  : xor 1
    x = dppadd<0x4E>(x);    // quad_perm [2,3,0,1]  : xor 2
    x = dppadd<0x141>(x);   // row_half_mirror      : xor 7 (combines quads)
    return x;
}
// full wave64 sum, broadcast via readlane(63)
__device__ __forceinline__ float wsum64(float x) {
    x = dppadd<0x111>(x); x = dppadd<0x112>(x); x = dppadd<0x114>(x);
    x = dppadd<0x118>(x); x = dppadd<0x142>(x); x = dppadd<0x143>(x);
    return __int_as_float(__builtin_amdgcn_readlane(__float_as_int(x), 63));
}
__device__ __forceinline__ void wsum64_2(float& a, float& b) {
#define DPP_STEP(ctrl) \
    a = dppadd<ctrl>(a); b = dppadd<ctrl>(b);
    DPP_STEP(0x111) DPP_STEP(0x112) DPP_STEP(0x114) DPP_STEP(0x118) DPP_STEP(0x142) DPP_STEP(0x143)
#undef DPP_STEP
    a = __int_as_float(__builtin_amdgcn_readlane(__float_as_int(a), 63));
    b = __int_as_float(__builtin_amdgcn_readlane(__float_as_int(b), 63));
}
__device__ __forceinline__ double wred64d(double v) {
    v += __shfl_xor(v, 1);  v += __shfl_xor(v, 2);  v += __shfl_xor(v, 4);
    v += __shfl_xor(v, 8);  v += __shfl_xor(v, 16); v += __shfl_xor(v, 32);
    return v;
}

__device__ __forceinline__ float dot16(const float4* r, const float4* m) {
    float d = 0.f;
#pragma unroll
    for (int j = 0; j < 4; ++j)
        d += r[j].x * m[j].x + r[j].y * m[j].y + r[j].z * m[j].z + r[j].w * m[j].w;
    return d;
}

// ---------------------------------------------------------------------------
// Kernel 1: per-group Karcher mean. 256 threads = 32 member-slots x 8 dim-octs.
// ---------------------------------------------------------------------------
__global__ __launch_bounds__(256) void proto_kernel(
        const float* __restrict__ reps,
        const int*   __restrict__ targets,
        float* __restrict__ mu_out,
        float* __restrict__ mu2_out) {
    __shared__ int   wtmp[4][WCAP];
    __shared__ int   wcnt[4];
    __shared__ int   woff[4];
    __shared__ int   mlist[MCAP];
    __shared__ int   s_n;
    __shared__ float xs[64 * D_N];       // expmapped rows, tiles 0/1 (32 KiB)
    __shared__ float sc_l[MCAP];         // expmap scale, extra tiles only
    __shared__ float x2_l[MCAP];         // |xp|^2, extra tiles only
    __shared__ float w_l[MCAP];
    __shared__ float cb_l[MCAP];
    __shared__ float mu_lds[D_N];
    __shared__ float part[4][D_N];
    __shared__ float scbp[4];

    const int p    = blockIdx.x;
    const int tid  = threadIdx.x;
    const int wv   = tid >> 6;
    const int lane = tid & 63;
    const int mloc = tid >> 3;           // member slot 0..31
    const int q    = tid & 7;            // dim oct: dims [16q, 16q+16)

    // ---- membership scan: wave wv scans targets[wv*1024 .. +1024)
    {
        const unsigned long long lowmask = (1ULL << lane) - 1ULL;
        int cnt = 0;
        for (int r = 0; r < 16; ++r) {
            int b = (wv << 10) + (r << 6) + lane;
            bool mm = (targets[b] == p);
            unsigned long long mk = __ballot(mm);
            if (mm) {
                int pos = cnt + __popcll(mk & lowmask);
                if (pos < WCAP) wtmp[wv][pos] = b;
            }
            cnt += __popcll(mk);
        }
        if (cnt > WCAP) cnt = WCAP;
        if (lane == 0) wcnt[wv] = cnt;
    }
    __syncthreads();
    if (tid == 0) {
        int c0 = wcnt[0], c1 = wcnt[1], c2 = wcnt[2], c3 = wcnt[3];
        woff[0] = 0; woff[1] = c0; woff[2] = c0 + c1; woff[3] = c0 + c1 + c2;
        int nn = c0 + c1 + c2 + c3;
        s_n = (nn > MCAP) ? MCAP : nn;
    }
    __syncthreads();
    {
        int base = woff[wv], cnt = wcnt[wv];
        for (int i = lane; i < cnt; i += 64) mlist[base + i] = wtmp[wv][i];
    }
    __syncthreads();

    const int   n       = s_n;
    const float inv_cnt = 1.0f / fmaxf((float)n, 1.0f);
    const int   NT      = (n + 31) >> 5;
    const float4* reps4 = (const float4*)reps;

    // ---- register tiles 0,1: load raw, expmap in place, stage to xs
    float4 r0[4], r1[4];
    float  x2_0 = 0.f, x2_1 = 0.f;
    const bool a0 = (mloc < n);
    const bool a1 = (mloc + 32 < n);
    {
        int b0 = a0 ? mlist[mloc] : 0;
#pragma unroll
        for (int j = 0; j < 4; ++j) r0[j] = reps4[(size_t)b0 * 32 + q * 4 + j];
        float ss = 0.f;
#pragma unroll
        for (int j = 0; j < 4; ++j)
            ss += r0[j].x * r0[j].x + r0[j].y * r0[j].y + r0[j].z * r0[j].z + r0[j].w * r0[j].w;
        ss = red8(ss);
        float nn = fmaxf(sqrtf(ss), EPSF);
        float sv = tanhf(nn) / nn;
#pragma unroll
        for (int j = 0; j < 4; ++j) { r0[j].x *= sv; r0[j].y *= sv; r0[j].z *= sv; r0[j].w *= sv; }
        x2_0 = ss * sv * sv;
        if (a0) {
#pragma unroll
            for (int j = 0; j < 4; ++j)
                *(float4*)&xs[mloc * D_N + q * 16 + j * 4] = r0[j];
        }
    }
    {
        int b1 = a1 ? mlist[mloc + 32] : 0;
#pragma unroll
        for (int j = 0; j < 4; ++j) r1[j] = reps4[(size_t)b1 * 32 + q * 4 + j];
        float ss = 0.f;
#pragma unroll
        for (int j = 0; j < 4; ++j)
            ss += r1[j].x * r1[j].x + r1[j].y * r1[j].y + r1[j].z * r1[j].z + r1[j].w * r1[j].w;
        ss = red8(ss);
        float nn = fmaxf(sqrtf(ss), EPSF);
        float sv = tanhf(nn) / nn;
#pragma unroll
        for (int j = 0; j < 4; ++j) { r1[j].x *= sv; r1[j].y *= sv; r1[j].z *= sv; r1[j].w *= sv; }
        x2_1 = ss * sv * sv;
        if (a1) {
#pragma unroll
            for (int j = 0; j < 4; ++j)
                *(float4*)&xs[(mloc + 32) * D_N + q * 16 + j * 4] = r1[j];
        }
    }
    // extra tiles (rare): precompute sc, x2
    for (int ti = 2; ti < NT; ++ti) {
        int  me = ti * 32 + mloc;
        bool ae = (me < n);
        int  b  = ae ? mlist[me] : 0;
        float ss = 0.f;
#pragma unroll
        for (int j = 0; j < 4; ++j) {
            float4 t4 = reps4[(size_t)b * 32 + q * 4 + j];
            ss += t4.x * t4.x + t4.y * t4.y + t4.z * t4.z + t4.w * t4.w;
        }
        ss = red8(ss);
        if (ae && q == 0) {
            float nn = fmaxf(sqrtf(ss), EPSF);
            float sv = tanhf(nn) / nn;
            sc_l[me] = sv;
            x2_l[me] = ss * sv * sv;
        }
    }
    __syncthreads();

    // ---- init: Euclidean mean of expmapped rows (member-parallel, lane=dim)
    float2 S; S.x = 0.f; S.y = 0.f;
    for (int ti = 0; ti < NT; ++ti) {
        for (int k = 0; k < 8; ++k) {
            int m = ti * 32 + wv * 8 + k;
            if (m < n) {
                float2 xv;
                if (ti < 2) {
                    xv = *(const float2*)&xs[m * D_N + 2 * lane];
                } else {
                    int b = mlist[m];
                    float2 rv = ((const float2*)reps)[(size_t)b * 64 + lane];
                    float s = sc_l[m];
                    xv.x = rv.x * s; xv.y = rv.y * s;
                }
                S.x += xv.x; S.y += xv.y;
            }
        }
    }
    *(float2*)&part[wv][2 * lane] = S;
    __syncthreads();
    float2 muf; muf.x = 0.f; muf.y = 0.f;
#pragma unroll
    for (int w2 = 0; w2 < 4; ++w2) {
        float2 pv = *(const float2*)&part[w2][2 * lane];
        muf.x += pv.x; muf.y += pv.y;
    }
    muf.x *= inv_cnt; muf.y *= inv_cnt;
    float m2   = wsum64(muf.x * muf.x + muf.y * muf.y);
    float nrm  = fmaxf(sqrtf(m2), EPSF);
    float fac  = fminf(1.0f, MAXNORM / nrm);
    muf.x *= fac; muf.y *= fac;
    float mu2 = m2 * fac * fac;
    if (wv == 0) *(float2*)&mu_lds[2 * lane] = muf;
    __syncthreads();

    // ---- Karcher iterations
    for (int it = 0; it < ITERS; ++it) {
        // phase 1: member-slot layout, dots from registers + mu_lds slice
        float4 ms[4];
        {
            const float4* mu4 = (const float4*)mu_lds;
#pragma unroll
            for (int j = 0; j < 4; ++j) ms[j] = mu4[q * 4 + j];
        }
        {
            float d = red8(dot16(r0, ms));
            float ca  = 1.0f - 2.0f * d + mu2;
            float cbv = 1.0f - x2_0;
            float den = fmaxf(1.0f - 2.0f * d + x2_0 * mu2, EPSF);
            float iv  = 1.0f / den;
            if (a0 && q == 0) { w_l[mloc] = ca * iv; cb_l[mloc] = cbv * iv; }
        }
        {
            float d = red8(dot16(r1, ms));
            float ca  = 1.0f - 2.0f * d + mu2;
            float cbv = 1.0f - x2_1;
            float den = fmaxf(1.0f - 2.0f * d + x2_1 * mu2, EPSF);
            float iv  = 1.0f / den;
            if (a1 && q == 0) { w_l[mloc + 32] = ca * iv; cb_l[mloc + 32] = cbv * iv; }
        }
        for (int ti = 2; ti < NT; ++ti) {
            int  me = ti * 32 + mloc;
            bool ae = (me < n);
            int  b  = ae ? mlist[me] : 0;
            float d = 0.f;
#pragma unroll
            for (int j = 0; j < 4; ++j) {
                float4 t4 = reps4[(size_t)b * 32 + q * 4 + j];
                d += t4.x * ms[j].x + t4.y * ms[j].y + t4.z * ms[j].z + t4.w * ms[j].w;
            }
            d = red8(d);
            if (ae) {
                float sv  = sc_l[me];
                float x2v = x2_l[me];
                float dp  = sv * d;
                float ca  = 1.0f - 2.0f * dp + mu2;
                float cbv = 1.0f - x2v;
                float den = fmaxf(1.0f - 2.0f * dp + x2v * mu2, EPSF);
                float iv  = 1.0f / den;
                if (q == 0) { w_l[me] = ca * iv; cb_l[me] = cbv * iv; }
            }
        }
        __syncthreads();   // B1: w_l/cb_l ready

        // phase c: lane=dim weighted row sum, member-parallel across waves
        float2 S2; S2.x = 0.f; S2.y = 0.f;
        float  scb = 0.f;
        for (int ti = 0; ti < NT; ++ti) {
            for (int k = 0; k < 8; ++k) {
                int m = ti * 32 + wv * 8 + k;
                if (m < n) {
                    float wvv = w_l[m];
                    scb += cb_l[m];
                    if (ti < 2) {
                        float2 xv = *(const float2*)&xs[m * D_N + 2 * lane];
                        S2.x += wvv * xv.x; S2.y += wvv * xv.y;
                    } else {
                        int b = mlist[m];
                        float2 rv = ((const float2*)reps)[(size_t)b * 64 + lane];
                        float we = wvv * sc_l[m];
                        S2.x += we * rv.x; S2.y += we * rv.y;
                    }
                }
            }
        }
        *(float2*)&part[wv][2 * lane] = S2;
        if (lane == 0) scbp[wv] = scb;
        __syncthreads();   // B2: partials ready

        // combine + mobius update (redundant on every wave)
        float2 T; T.x = 0.f; T.y = 0.f;
#pragma unroll
        for (int w2 = 0; w2 < 4; ++w2) {
            float2 pv = *(const float2*)&part[w2][2 * lane];
            T.x += pv.x; T.y += pv.y;
        }
        float scbt = scbp[0] + scbp[1] + scbp[2] + scbp[3];
        float scs  = scbt * inv_cnt;
        float2 md;
        md.x = T.x * inv_cnt - scs * muf.x;
        md.y = T.y * inv_cnt - scs * muf.y;

        float A0 = md.x * md.x + md.y * md.y;     // |md|^2 partial
        float A1 = muf.x * md.x + muf.y * md.y;   // <mu,md> partial
        wsum64_2(A0, A1);
        float ca  = 1.0f + 2.0f * A1 + A0;
        float cbv = 1.0f - mu2;
        float den = fmaxf(1.0f + 2.0f * A1 + mu2 * A0, EPSF);
        float iv  = 1.0f / den;
        float2 tv;
        tv.x = (ca * muf.x + cbv * md.x) * iv;
        tv.y = (ca * muf.y + cbv * md.y) * iv;
        float t2   = (ca * ca * mu2 + 2.0f * ca * cbv * A1 + cbv * cbv * A0) * iv * iv;
        float nrm2 = fmaxf(sqrtf(t2), EPSF);
        float fc   = fminf(1.0f, MAXNORM / nrm2);
        muf.x = tv.x * fc; muf.y = tv.y * fc;
        mu2   = t2 * fc * fc;

        if (wv == 0) *(float2*)&mu_lds[2 * lane] = muf;
        __syncthreads();   // B3: mu_lds fresh for next phase 1
    }

    // final project_to_ball
    {
        float nf = fmaxf(sqrtf(mu2), EPSF);
        float ff = fminf(1.0f, MAXNORM / nf);
        muf.x *= ff; muf.y *= ff;
        mu2 = mu2 * ff * ff;
    }
    if (wv == 0) {
        ((float2*)(mu_out + (size_t)p * D_N))[lane] = muf;
        if (lane == 0) mu2_out[p] = mu2;
    }
}

// ---------------------------------------------------------------------------
// Kernel 2: Poincare distance per upper-tri pair (wave per pair). No fences —
// cross-kernel visibility comes from the stream dependency.
// ---------------------------------------------------------------------------
__global__ __launch_bounds__(256) void dist_kernel(
        const float* __restrict__ mu,
        const float* __restrict__ mu2s,
        float* __restrict__ dB) {
    const int wv   = threadIdx.x >> 6;
    const int lane = threadIdx.x & 63;
    int k = blockIdx.x * 4 + wv;       // grid = NPAIRS/4 exactly

    int i = (int)((float)P_N - 0.5f -
                  sqrtf(((float)P_N - 0.5f) * ((float)P_N - 0.5f) - 2.0f * (float)k));
    if (i < 0) i = 0;
    while ((i + 1) * (2 * P_N - i - 2) / 2 <= k) ++i;
    while (i * (2 * P_N - i - 1) / 2 > k) --i;
    int j = k - i * (2 * P_N - i - 1) / 2 + i + 1;

    float2 a = ((const float2*)(mu + (size_t)i * D_N))[lane];
    float2 b = ((const float2*)(mu + (size_t)j * D_N))[lane];
    float dx = a.x - b.x, dy = a.y - b.y;
    float d2 = wsum64(dx * dx + dy * dy);
    float ai = fmaxf(1.0f - mu2s[i], EPSF);
    float aj = fmaxf(1.0f - mu2s[j], EPSF);
    float z  = 1.0f + 2.0f * d2 / fmaxf(ai * aj, EPSF);
    z = fmaxf(z, 1.0f + EPSF);
    if (lane == 0) dB[k] = acoshf(z);
}

// ---------------------------------------------------------------------------
// Kernel 3: Pearson correlation, single block.
// ---------------------------------------------------------------------------
__global__ __launch_bounds__(256) void corr_kernel(
        const float* __restrict__ dB,
        const int*   __restrict__ dT,
        float* __restrict__ out) {
    __shared__ double sh[4][5];
    const int tid  = threadIdx.x;
    const int wv   = tid >> 6;
    const int lane = tid & 63;

    double s1 = 0.0, s2 = 0.0, st = 0.0, st2 = 0.0, sbt = 0.0;
    for (int e = tid; e < NPAIRS; e += 256) {
        double bb = (double)dB[e];
        double tt = (double)dT[e];
        s1 += bb; s2 += bb * bb; st += tt; st2 += tt * tt; sbt += bb * tt;
    }
    s1  = wred64d(s1);
    s2  = wred64d(s2);
    st  = wred64d(st);
    st2 = wred64d(st2);
    sbt = wred64d(sbt);
    if (lane == 0) {
        sh[wv][0] = s1; sh[wv][1] = s2; sh[wv][2] = st;
        sh[wv][3] = st2; sh[wv][4] = sbt;
    }
    __syncthreads();
    if (tid == 0) {
        double t1 = 0, t2 = 0, t3 = 0, t4 = 0, t5 = 0;
        for (int w = 0; w < 4; ++w) {
            t1 += sh[w][0]; t2 += sh[w][1]; t3 += sh[w][2];
            t4 += sh[w][3]; t5 += sh[w][4];
        }
        const double nn = (double)NPAIRS;
        double mb  = t1 / nn;
        double mt  = t3 / nn;
        double cov = t5 - nn * mb * mt;
        double vb  = t2 - nn * mb * mb;
        double vt  = t4 - nn * mt * mt;
        double corr = cov / sqrt(vb * vt);
        double res  = isnan(corr) ? 1.0 : (1.0 - corr);
        out[0] = (float)res;
    }
}

// ---------------------------------------------------------------------------
extern "C" void kernel_launch(void* const* d_in, const int* in_sizes, int n_in,
                              void* d_out, int out_size, void* d_ws, size_t ws_size,
                              hipStream_t stream) {
    const float* reps    = (const float*)d_in[0];
    const int*   targets = (const int*)d_in[1];
    const int*   dT      = (const int*)d_in[2];
    float* out = (float*)d_out;

    float* mu   = (float*)d_ws;                 // P*D    = 16384 f
    float* mu2s = mu + (size_t)P_N * D_N;       // P
    float* dB   = mu2s + P_N;                   // NPAIRS

    proto_kernel<<<P_N, 256, 0, stream>>>(reps, targets, mu, mu2s);
    dist_kernel<<<NPAIRS / 4, 256, 0, stream>>>(mu, mu2s, dB);
    corr_kernel<<<1, 256, 0, stream>>>(dB, dT, out);
}

// Round 7
// 38.143 us; speedup vs baseline: 2.3692x; 1.0119x over previous
//
#include <hip/hip_runtime.h>
#include <math.h>

#define EPSF    1e-6f
#define B_N     4096
#define P_N     128
#define D_N     128
#define NPAIRS  (P_N * (P_N - 1) / 2)   // 8128
#define ITERS   10
#define MAXNORM 0.99999f                 // (1 - 1e-5) / sqrt(c), c = 1
#define MCAP    512                      // max members per group handled
#define WCAP    128                      // per-wave member list capacity
#define XCAP    96                       // rows staged in LDS
#define ZCAP    48                       // zero-filled + fully-unrolled region

// ---------------------------------------------------------------------------
// DPP helpers (ctrl is a template param: must be a compile-time constant)
// ---------------------------------------------------------------------------
template <int CTRL>
__device__ __forceinline__ float dppadd(float x) {
    float t = __int_as_float(__builtin_amdgcn_update_dpp(
        0, __float_as_int(x), CTRL, 0xf, 0xf, true));
    return x + t;
}
// sum over aligned groups of 8 lanes (result in every lane of the group)
__device__ __forceinline__ float red8(float x) {
    x = dppadd<0xB1>(x);    // quad_perm [1,0,3,2]  : xor 1
    x = dppadd<0x4E>(x);    // quad_perm [2,3,0,1]  : xor 2
    x = dppadd<0x141>(x);   // row_half_mirror      : xor 7
    return x;
}
// full wave64 sum, broadcast via readlane(63)
__device__ __forceinline__ float wsum64(float x) {
    x = dppadd<0x111>(x); x = dppadd<0x112>(x); x = dppadd<0x114>(x);
    x = dppadd<0x118>(x); x = dppadd<0x142>(x); x = dppadd<0x143>(x);
    return __int_as_float(__builtin_amdgcn_readlane(__float_as_int(x), 63));
}
__device__ __forceinline__ void wsum64_2(float& a, float& b) {
#define DPP_STEP(ctrl) \
    a = dppadd<ctrl>(a); b = dppadd<ctrl>(b);
    DPP_STEP(0x111) DPP_STEP(0x112) DPP_STEP(0x114) DPP_STEP(0x118) DPP_STEP(0x142) DPP_STEP(0x143)
#undef DPP_STEP
    a = __int_as_float(__builtin_amdgcn_readlane(__float_as_int(a), 63));
    b = __int_as_float(__builtin_amdgcn_readlane(__float_as_int(b), 63));
}
__device__ __forceinline__ double wred64d(double v) {
    v += __shfl_xor(v, 1);  v += __shfl_xor(v, 2);  v += __shfl_xor(v, 4);
    v += __shfl_xor(v, 8);  v += __shfl_xor(v, 16); v += __shfl_xor(v, 32);
    return v;
}

// ---------------------------------------------------------------------------
// Kernel 1: per-group Karcher mean.
// Setup (4 waves): ballot membership scan; stage expmapped rows into LDS with
// float4-index XOR swizzle (c ^= m&7). Then waves 1-3 EXIT; wave 0 runs the
// 10 iterations alone: zero barriers, all LDS traffic wave-local.
// ---------------------------------------------------------------------------
__global__ __launch_bounds__(256) void proto_kernel(
        const float* __restrict__ reps,
        const int*   __restrict__ targets,
        float* __restrict__ mu_out,
        float* __restrict__ mu2_out,
        int*   __restrict__ counter) {
    __shared__ int    wtmp[4][WCAP];
    __shared__ int    wcnt[4];
    __shared__ int    woff[4];
    __shared__ int    mlist[MCAP];
    __shared__ int    s_n;
    __shared__ float4 xs4[XCAP * 32];    // 49152 B; row m, f4-col c at [m*32 + (c^(m&7))]
    __shared__ float  sc_l[MCAP];
    __shared__ float  x2_l[MCAP];
    __shared__ float  w_l[MCAP];
    __shared__ float  cb_l[MCAP];
    __shared__ float  mu_lds[D_N];

    const int p    = blockIdx.x;
    const int tid  = threadIdx.x;
    const int wv   = tid >> 6;
    const int lane = tid & 63;
    const int mloc = tid >> 3;           // member slot 0..31 (block-wide)
    const int q    = tid & 7;            // dim oct: f4 cols [4q, 4q+4)

    if (p == 0 && tid == 0) counter[0] = 0;   // for distcorr last-block

    // ---- membership scan: wave wv scans targets[wv*1024 .. +1024)
    {
        const unsigned long long lowmask = (1ULL << lane) - 1ULL;
        int cnt = 0;
        for (int r = 0; r < 16; ++r) {
            int b = (wv << 10) + (r << 6) + lane;
            bool mm = (targets[b] == p);
            unsigned long long mk = __ballot(mm);
            if (mm) {
                int pos = cnt + __popcll(mk & lowmask);
                if (pos < WCAP) wtmp[wv][pos] = b;
            }
            cnt += __popcll(mk);
        }
        if (cnt > WCAP) cnt = WCAP;
        if (lane == 0) wcnt[wv] = cnt;
    }
    __syncthreads();
    if (tid == 0) {
        int c0 = wcnt[0], c1 = wcnt[1], c2 = wcnt[2], c3 = wcnt[3];
        woff[0] = 0; woff[1] = c0; woff[2] = c0 + c1; woff[3] = c0 + c1 + c2;
        int nn = c0 + c1 + c2 + c3;
        s_n = (nn > MCAP) ? MCAP : nn;
    }
    __syncthreads();
    {
        int base = woff[wv], cnt = wcnt[wv];
        for (int i = lane; i < cnt; i += 64) mlist[base + i] = wtmp[wv][i];
    }
    __syncthreads();

    const int   n       = s_n;
    const float inv_cnt = 1.0f / fmaxf((float)n, 1.0f);
    const int   n_st    = (n < XCAP) ? n : XCAP;
    const float4* reps4 = (const float4*)reps;

    // ---- stage rows: load raw, expmap, write swizzled. Zero-fill [n, ZCAP).
    for (int k = 0; k < 3; ++k) {
        int m = k * 32 + mloc;
        if (m < n_st) {
            int b = mlist[m];
            float4 r[4];
            float ss = 0.f;
#pragma unroll
            for (int j = 0; j < 4; ++j) {
                r[j] = reps4[(size_t)b * 32 + 4 * q + j];
                ss += r[j].x * r[j].x + r[j].y * r[j].y + r[j].z * r[j].z + r[j].w * r[j].w;
            }
            ss = red8(ss);
            float nn = fmaxf(sqrtf(ss), EPSF);
            float sv = tanhf(nn) / nn;
#pragma unroll
            for (int j = 0; j < 4; ++j) {
                r[j].x *= sv; r[j].y *= sv; r[j].z *= sv; r[j].w *= sv;
                xs4[m * 32 + ((4 * q + j) ^ (m & 7))] = r[j];
            }
            if (q == 0) { sc_l[m] = sv; x2_l[m] = ss * sv * sv; }
        } else if (m < ZCAP) {
            float4 z; z.x = 0.f; z.y = 0.f; z.z = 0.f; z.w = 0.f;
#pragma unroll
            for (int j = 0; j < 4; ++j)
                xs4[m * 32 + ((4 * q + j) ^ (m & 7))] = z;
            if (q == 0) { sc_l[m] = 0.f; x2_l[m] = 0.f; }
        }
    }
    // extra members beyond XCAP: scale/x2 only (rows stay in global)
    for (int k = 3; k * 32 < n; ++k) {
        int m = k * 32 + mloc;
        if (m < n && m < MCAP) {
            int b = mlist[m];
            float ss = 0.f;
#pragma unroll
            for (int j = 0; j < 4; ++j) {
                float4 t4 = reps4[(size_t)b * 32 + 4 * q + j];
                ss += t4.x * t4.x + t4.y * t4.y + t4.z * t4.z + t4.w * t4.w;
            }
            ss = red8(ss);
            if (q == 0) {
                float nn = fmaxf(sqrtf(ss), EPSF);
                float sv = tanhf(nn) / nn;
                sc_l[m] = sv;
                x2_l[m] = ss * sv * sv;
            }
        }
    }
    __syncthreads();
    if (wv != 0) return;                 // ---- wave 0 continues ALONE ----

    const int l   = tid;                 // 0..63
    const int grp = l >> 3;              // q still = l&7
    const float*  xsf   = (const float*)xs4;
    const float2* reps2 = (const float2*)reps;

    // ---- init: Euclidean mean of expmapped rows (lane = dim)
    float2 S; S.x = 0.f; S.y = 0.f;
#pragma unroll
    for (int m = 0; m < ZCAP; ++m) {
        float2 xv = *(const float2*)&xsf[(m * 32 + ((l >> 1) ^ (m & 7))) * 4 + (l & 1) * 2];
        S.x += xv.x; S.y += xv.y;
    }
    for (int m = ZCAP; m < n; ++m) {
        float2 xv;
        if (m < XCAP) {
            xv = *(const float2*)&xsf[(m * 32 + ((l >> 1) ^ (m & 7))) * 4 + (l & 1) * 2];
        } else {
            int b = mlist[m];
            float2 rv = reps2[(size_t)b * 64 + l];
            float s = sc_l[m];
            xv.x = rv.x * s; xv.y = rv.y * s;
        }
        S.x += xv.x; S.y += xv.y;
    }
    float2 muf; muf.x = S.x * inv_cnt; muf.y = S.y * inv_cnt;
    float m2   = wsum64(muf.x * muf.x + muf.y * muf.y);
    float nrm  = fmaxf(sqrtf(m2), EPSF);
    float fac  = fminf(1.0f, MAXNORM / nrm);
    muf.x *= fac; muf.y *= fac;
    float mu2 = m2 * fac * fac;
    ((float2*)mu_lds)[l] = muf;

    // ---- Karcher iterations (single wave, zero barriers)
    for (int it = 0; it < ITERS; ++it) {
        const float4* mu4 = (const float4*)mu_lds;
        float4 ms[4];
#pragma unroll
        for (int j = 0; j < 4; ++j) ms[j] = mu4[4 * q + j];

        // phase 1: dots per member slot (grp = slot within tile of 8)
#pragma unroll
        for (int t = 0; t < 6; ++t) {
            int m = t * 8 + grp;
            float dot = 0.f;
#pragma unroll
            for (int j = 0; j < 4; ++j) {
                float4 a = xs4[m * 32 + ((4 * q + j) ^ (m & 7))];
                dot += a.x * ms[j].x + a.y * ms[j].y + a.z * ms[j].z + a.w * ms[j].w;
            }
            float d   = red8(dot);
            float x2v = x2_l[m];
            float ca  = 1.0f - 2.0f * d + mu2;
            float cbv = 1.0f - x2v;
            float den = fmaxf(1.0f - 2.0f * d + x2v * mu2, EPSF);
            float iv  = 1.0f / den;
            bool  act = (m < n);
            float wvv = act ? ca * iv : 0.f;
            float cbb = act ? cbv * iv : 0.f;
            if (q == 0) { w_l[m] = wvv; cb_l[m] = cbb; }
        }
        for (int mb = ZCAP; mb < n; mb += 8) {
            int  m   = mb + grp;
            bool act = (m < n);
            float d, dp, x2v;
            if (mb + 7 < XCAP) {
                float dot = 0.f;
#pragma unroll
                for (int j = 0; j < 4; ++j) {
                    float4 a = xs4[m * 32 + ((4 * q + j) ^ (m & 7))];
                    dot += a.x * ms[j].x + a.y * ms[j].y + a.z * ms[j].z + a.w * ms[j].w;
                }
                d  = red8(dot);
                dp = d;                              // staged rows already expmapped
            } else {
                int b = act ? mlist[m] : 0;
                float dot = 0.f;
#pragma unroll
                for (int j = 0; j < 4; ++j) {
                    float4 a = reps4[(size_t)b * 32 + 4 * q + j];
                    dot += a.x * ms[j].x + a.y * ms[j].y + a.z * ms[j].z + a.w * ms[j].w;
                }
                d  = red8(dot);
                dp = sc_l[m < MCAP ? m : 0] * d;     // raw row: fold scale
            }
            x2v = x2_l[m < MCAP ? m : 0];
            float ca  = 1.0f - 2.0f * dp + mu2;
            float cbv = 1.0f - x2v;
            float den = fmaxf(1.0f - 2.0f * dp + x2v * mu2, EPSF);
            float iv  = 1.0f / den;
            float wvv = act ? ca * iv : 0.f;
            float cbb = act ? cbv * iv : 0.f;
            if (q == 0 && m < MCAP) { w_l[m] = wvv; cb_l[m] = cbb; }
        }

        // phase C: lane = dim weighted row sum (w broadcast from LDS)
        float2 S2; S2.x = 0.f; S2.y = 0.f;
        float  scb = 0.f;
#pragma unroll
        for (int m = 0; m < ZCAP; ++m) {
            float wvv = w_l[m];
            scb += cb_l[m];
            float2 xv = *(const float2*)&xsf[(m * 32 + ((l >> 1) ^ (m & 7))) * 4 + (l & 1) * 2];
            S2.x += wvv * xv.x; S2.y += wvv * xv.y;
        }
        for (int m = ZCAP; m < n; ++m) {
            float wvv = w_l[m];
            scb += cb_l[m];
            float2 xv;
            if (m < XCAP) {
                xv = *(const float2*)&xsf[(m * 32 + ((l >> 1) ^ (m & 7))) * 4 + (l & 1) * 2];
            } else {
                int b = mlist[m];
                float2 rv = reps2[(size_t)b * 64 + l];
                float s = sc_l[m];
                xv.x = rv.x * s; xv.y = rv.y * s;
            }
            S2.x += wvv * xv.x; S2.y += wvv * xv.y;
        }
        float scs = scb * inv_cnt;
        float2 md;
        md.x = S2.x * inv_cnt - scs * muf.x;
        md.y = S2.y * inv_cnt - scs * muf.y;

        // mu <- project(mobius_add(mu, md)); |t|^2 analytic
        float A0 = md.x * md.x + md.y * md.y;
        float A1 = muf.x * md.x + muf.y * md.y;
        wsum64_2(A0, A1);
        float ca  = 1.0f + 2.0f * A1 + A0;
        float cbv = 1.0f - mu2;
        float den = fmaxf(1.0f + 2.0f * A1 + mu2 * A0, EPSF);
        float iv  = 1.0f / den;
        float2 tv;
        tv.x = (ca * muf.x + cbv * md.x) * iv;
        tv.y = (ca * muf.y + cbv * md.y) * iv;
        float t2   = (ca * ca * mu2 + 2.0f * ca * cbv * A1 + cbv * cbv * A0) * iv * iv;
        float nrm2 = fmaxf(sqrtf(t2), EPSF);
        float fc   = fminf(1.0f, MAXNORM / nrm2);
        muf.x = tv.x * fc; muf.y = tv.y * fc;
        mu2   = t2 * fc * fc;
        ((float2*)mu_lds)[l] = muf;
    }

    // final project_to_ball
    {
        float nf = fmaxf(sqrtf(mu2), EPSF);
        float ff = fminf(1.0f, MAXNORM / nf);
        muf.x *= ff; muf.y *= ff;
        mu2 = mu2 * ff * ff;
    }
    ((float2*)(mu_out + (size_t)p * D_N))[l] = muf;
    if (l == 0) mu2_out[p] = mu2;
}

// ---------------------------------------------------------------------------
// Kernel 2: distances + Pearson, fused. 8 blocks x 1024 threads, thread=pair.
// mu staged in LDS with stride 129 (conflict-free scalar reads). Cheap
// last-block pattern (only 8 device fences total, vs R5's 2032).
// ---------------------------------------------------------------------------
__global__ __launch_bounds__(1024) void distcorr_kernel(
        const float* __restrict__ mu,
        const float* __restrict__ mu2s,
        const int*   __restrict__ dT,
        double* __restrict__ gpart,
        int*    __restrict__ counter,
        float*  __restrict__ out) {
    __shared__ float  lmu[P_N * 129];    // 66048 B (gfx950 allows >64KB static LDS)
    __shared__ float  lmu2[P_N];
    __shared__ double sh[16][5];
    __shared__ int    s_last;

    const int tid = threadIdx.x;
#pragma unroll
    for (int e = 0; e < 16; ++e) {
        int idx = tid + e * 1024;
        lmu[(idx >> 7) * 129 + (idx & 127)] = mu[idx];
    }
    if (tid < P_N) lmu2[tid] = mu2s[tid];
    __syncthreads();

    int k = blockIdx.x * 1024 + tid;
    double p0 = 0.0, p1 = 0.0, p2 = 0.0, p3 = 0.0, p4 = 0.0;
    if (k < NPAIRS) {
        int i = (int)(127.5f - sqrtf(127.5f * 127.5f - 2.0f * (float)k));
        if (i < 0) i = 0;
        while ((i + 1) * (2 * P_N - i - 2) / 2 <= k) ++i;
        while (i * (2 * P_N - i - 1) / 2 > k) --i;
        int j = k - i * (2 * P_N - i - 1) / 2 + i + 1;

        const float* ra = &lmu[i * 129];
        const float* rb = &lmu[j * 129];
        float a0 = 0.f, a1 = 0.f, a2 = 0.f, a3 = 0.f;
#pragma unroll
        for (int d = 0; d < D_N; d += 4) {
            float f0 = ra[d]     - rb[d];
            float f1 = ra[d + 1] - rb[d + 1];
            float f2 = ra[d + 2] - rb[d + 2];
            float f3 = ra[d + 3] - rb[d + 3];
            a0 += f0 * f0; a1 += f1 * f1; a2 += f2 * f2; a3 += f3 * f3;
        }
        float d2 = (a0 + a1) + (a2 + a3);
        float ai = fmaxf(1.f - lmu2[i], EPSF);
        float aj = fmaxf(1.f - lmu2[j], EPSF);
        float z  = 1.f + 2.f * d2 / fmaxf(ai * aj, EPSF);
        z = fmaxf(z, 1.f + EPSF);
        float dist = acoshf(z);
        double bb = (double)dist;
        double tt = (double)dT[k];
        p0 = bb; p1 = bb * bb; p2 = tt; p3 = tt * tt; p4 = bb * tt;
    }
    p0 = wred64d(p0); p1 = wred64d(p1); p2 = wred64d(p2);
    p3 = wred64d(p3); p4 = wred64d(p4);
    const int wid = tid >> 6, lane = tid & 63;
    if (lane == 0) {
        sh[wid][0] = p0; sh[wid][1] = p1; sh[wid][2] = p2;
        sh[wid][3] = p3; sh[wid][4] = p4;
    }
    __syncthreads();
    if (tid == 0) {
        double b0 = 0, b1 = 0, b2 = 0, b3 = 0, b4 = 0;
        for (int w = 0; w < 16; ++w) {
            b0 += sh[w][0]; b1 += sh[w][1]; b2 += sh[w][2];
            b3 += sh[w][3]; b4 += sh[w][4];
        }
        double* gp = gpart + (size_t)blockIdx.x * 5;
        gp[0] = b0; gp[1] = b1; gp[2] = b2; gp[3] = b3; gp[4] = b4;
        __threadfence();
        int old = atomicAdd(counter, 1);
        s_last = (old == (int)gridDim.x - 1) ? 1 : 0;
    }
    __syncthreads();
    if (!s_last) return;
    if (tid == 0) {
        __threadfence();
        double t0 = 0, t1 = 0, t2 = 0, t3 = 0, t4 = 0;
        for (int b = 0; b < 8; ++b) {
            t0 += gpart[b * 5 + 0]; t1 += gpart[b * 5 + 1]; t2 += gpart[b * 5 + 2];
            t3 += gpart[b * 5 + 3]; t4 += gpart[b * 5 + 4];
        }
        const double nn = (double)NPAIRS;
        double mb  = t0 / nn;
        double mt  = t2 / nn;
        double cov = t4 - nn * mb * mt;
        double vb  = t1 - nn * mb * mb;
        double vt  = t3 - nn * mt * mt;
        double corr = cov / sqrt(vb * vt);
        double res  = isnan(corr) ? 1.0 : (1.0 - corr);
        out[0] = (float)res;
    }
}

// ---------------------------------------------------------------------------
extern "C" void kernel_launch(void* const* d_in, const int* in_sizes, int n_in,
                              void* d_out, int out_size, void* d_ws, size_t ws_size,
                              hipStream_t stream) {
    const float* reps    = (const float*)d_in[0];
    const int*   targets = (const int*)d_in[1];
    const int*   dT      = (const int*)d_in[2];
    float* out = (float*)d_out;

    double* gpart   = (double*)d_ws;                          // 8*5 doubles
    int*    counter = (int*)((char*)d_ws + 320);              // 1 int
    float*  mu      = (float*)((char*)d_ws + 384);            // P*D floats
    float*  mu2s    = mu + (size_t)P_N * D_N;                 // P floats

    proto_kernel<<<P_N, 256, 0, stream>>>(reps, targets, mu, mu2s, counter);
    distcorr_kernel<<<8, 1024, 0, stream>>>(mu, mu2s, dT, gpart, counter, out);
}

// Round 8
// 31.305 us; speedup vs baseline: 2.8867x; 1.2184x over previous
//
#include <hip/hip_runtime.h>
#include <math.h>

#define EPSF    1e-6f
#define B_N     4096
#define P_N     128
#define D_N     128
#define NPAIRS  (P_N * (P_N - 1) / 2)   // 8128
#define ITERS   10
#define MAXNORM 0.99999f                 // (1 - 1e-5) / sqrt(c), c = 1
#define MCAP    512                      // max members per group handled
#define WCAP    128                      // per-wave member list capacity
#define SLOTS   64                       // staged slots (16 per wave, wave-owned)

// ---------------------------------------------------------------------------
// DPP helpers
// ---------------------------------------------------------------------------
template <int CTRL>
__device__ __forceinline__ float dppadd(float x) {
    float t = __int_as_float(__builtin_amdgcn_update_dpp(
        0, __float_as_int(x), CTRL, 0xf, 0xf, true));
    return x + t;
}
// sum over aligned groups of 8 lanes (result in every lane of the group)
__device__ __forceinline__ float red8(float x) {
    x = dppadd<0xB1>(x);    // quad_perm xor 1
    x = dppadd<0x4E>(x);    // quad_perm xor 2
    x = dppadd<0x141>(x);   // row_half_mirror: xor 7
    return x;
}
// full wave64 sum, broadcast via readlane(63)
__device__ __forceinline__ float wsum64(float x) {
    x = dppadd<0x111>(x); x = dppadd<0x112>(x); x = dppadd<0x114>(x);
    x = dppadd<0x118>(x); x = dppadd<0x142>(x); x = dppadd<0x143>(x);
    return __int_as_float(__builtin_amdgcn_readlane(__float_as_int(x), 63));
}
__device__ __forceinline__ void wsum64_2(float& a, float& b) {
#define DPP_STEP(ctrl) \
    a = dppadd<ctrl>(a); b = dppadd<ctrl>(b);
    DPP_STEP(0x111) DPP_STEP(0x112) DPP_STEP(0x114) DPP_STEP(0x118) DPP_STEP(0x142) DPP_STEP(0x143)
#undef DPP_STEP
    a = __int_as_float(__builtin_amdgcn_readlane(__float_as_int(a), 63));
    b = __int_as_float(__builtin_amdgcn_readlane(__float_as_int(b), 63));
}
__device__ __forceinline__ double wred64d(double v) {
    v += __shfl_xor(v, 1);  v += __shfl_xor(v, 2);  v += __shfl_xor(v, 4);
    v += __shfl_xor(v, 8);  v += __shfl_xor(v, 16); v += __shfl_xor(v, 32);
    return v;
}
__device__ __forceinline__ float dot16(const float4* r, const float4* m) {
    float d = 0.f;
#pragma unroll
    for (int j = 0; j < 4; ++j)
        d += r[j].x * m[j].x + r[j].y * m[j].y + r[j].z * m[j].z + r[j].w * m[j].w;
    return d;
}

// ---------------------------------------------------------------------------
// Kernel 1: per-group Karcher mean. 4 waves, wave-aligned member ownership:
// wave wv owns slots [wv*16, wv*16+16) -> xs/w_l/cb_l/sc/x2 are wave-private.
// ONE barrier per iteration (partial combine); mobius redundant on all waves;
// mu_lds same-value multi-writer (benign); part[]/scbp[] double-buffered.
// ---------------------------------------------------------------------------
__global__ __launch_bounds__(256) void proto_kernel(
        const float* __restrict__ reps,
        const int*   __restrict__ targets,
        float* __restrict__ mu_out,
        float* __restrict__ mu2_out,
        int*   __restrict__ counter) {
    __shared__ int    wtmp[4][WCAP];
    __shared__ int    wcnt[4];
    __shared__ int    woff[4];
    __shared__ int    mlist[MCAP];
    __shared__ int    s_n;
    __shared__ float4 xs4[SLOTS * 32];   // 32768 B; row m, f4-col c at [m*32 + (c^(m&7))]
    __shared__ float  sc_l[MCAP];
    __shared__ float  x2_l[MCAP];
    __shared__ float  w_l[MCAP];
    __shared__ float  cb_l[MCAP];
    __shared__ float  mu_lds[D_N];
    __shared__ float  part[2][4][D_N];   // double-buffered by iteration parity
    __shared__ float  scbp[2][4];

    const int p    = blockIdx.x;
    const int tid  = threadIdx.x;
    const int wv   = tid >> 6;
    const int lane = tid & 63;
    const int grp  = lane >> 3;          // 8-lane group 0..7
    const int q    = lane & 7;           // f4 cols [4q, 4q+4)

    if (p == 0 && tid == 0) counter[0] = 0;   // for distcorr last-block

    // ---- membership scan: wave wv scans targets[wv*1024 .. +1024), loads hoisted
    {
        int tg[16];
#pragma unroll
        for (int r = 0; r < 16; ++r) tg[r] = targets[(wv << 10) + (r << 6) + lane];
        const unsigned long long lowmask = (1ULL << lane) - 1ULL;
        int cnt = 0;
#pragma unroll
        for (int r = 0; r < 16; ++r) {
            bool mm = (tg[r] == p);
            unsigned long long mk = __ballot(mm);
            if (mm) {
                int pos = cnt + __popcll(mk & lowmask);
                if (pos < WCAP) wtmp[wv][pos] = (wv << 10) + (r << 6) + lane;
            }
            cnt += __popcll(mk);
        }
        if (cnt > WCAP) cnt = WCAP;
        if (lane == 0) wcnt[wv] = cnt;
    }
    __syncthreads();
    if (tid == 0) {
        int c0 = wcnt[0], c1 = wcnt[1], c2 = wcnt[2], c3 = wcnt[3];
        woff[0] = 0; woff[1] = c0; woff[2] = c0 + c1; woff[3] = c0 + c1 + c2;
        int nn = c0 + c1 + c2 + c3;
        s_n = (nn > MCAP) ? MCAP : nn;
    }
    __syncthreads();
    {
        int base = woff[wv], cnt = wcnt[wv];
        for (int i = lane; i < cnt; i += 64) mlist[base + i] = wtmp[wv][i];
    }
    __syncthreads();                     // last block-wide barrier of setup

    const int   n       = s_n;
    const float inv_cnt = 1.0f / fmaxf((float)n, 1.0f);
    const float4* reps4 = (const float4*)reps;
    const float2* reps2 = (const float2*)reps;

    const int mA = wv * 16 + grp;        // this group's slot 0
    const int mB = mA + 8;               // this group's slot 1

    // ---- stage own slots: load raw, expmap, write swizzled; zero-fill if !act
    float4 rA[4], rB[4];
    {
        bool act = (mA < n);
        int  b   = act ? mlist[mA] : 0;
        float ss = 0.f;
#pragma unroll
        for (int j = 0; j < 4; ++j) {
            rA[j] = reps4[(size_t)b * 32 + 4 * q + j];
            ss += rA[j].x * rA[j].x + rA[j].y * rA[j].y + rA[j].z * rA[j].z + rA[j].w * rA[j].w;
        }
        ss = red8(ss);
        float nn = fmaxf(sqrtf(ss), EPSF);
        float sv = act ? (tanhf(nn) / nn) : 0.f;
#pragma unroll
        for (int j = 0; j < 4; ++j) {
            rA[j].x *= sv; rA[j].y *= sv; rA[j].z *= sv; rA[j].w *= sv;
            xs4[mA * 32 + ((4 * q + j) ^ (mA & 7))] = rA[j];
        }
        if (q == 0) { sc_l[mA] = sv; x2_l[mA] = act ? ss * sv * sv : 0.f; }
    }
    {
        bool act = (mB < n);
        int  b   = act ? mlist[mB] : 0;
        float ss = 0.f;
#pragma unroll
        for (int j = 0; j < 4; ++j) {
            rB[j] = reps4[(size_t)b * 32 + 4 * q + j];
            ss += rB[j].x * rB[j].x + rB[j].y * rB[j].y + rB[j].z * rB[j].z + rB[j].w * rB[j].w;
        }
        ss = red8(ss);
        float nn = fmaxf(sqrtf(ss), EPSF);
        float sv = act ? (tanhf(nn) / nn) : 0.f;
#pragma unroll
        for (int j = 0; j < 4; ++j) {
            rB[j].x *= sv; rB[j].y *= sv; rB[j].z *= sv; rB[j].w *= sv;
            xs4[mB * 32 + ((4 * q + j) ^ (mB & 7))] = rB[j];
        }
        if (q == 0) { sc_l[mB] = sv; x2_l[mB] = act ? ss * sv * sv : 0.f; }
    }
    // fallback members (n > SLOTS), owner wave = ((m>>4)&3): sc/x2 only
    for (int mb = SLOTS + wv * 16; mb < n; mb += 64) {
#pragma unroll
        for (int t = 0; t < 2; ++t) {
            int  m   = mb + grp + 8 * t;
            bool act = (m < n);
            int  b   = act ? mlist[m] : 0;
            float ss = 0.f;
#pragma unroll
            for (int j = 0; j < 4; ++j) {
                float4 t4 = reps4[(size_t)b * 32 + 4 * q + j];
                ss += t4.x * t4.x + t4.y * t4.y + t4.z * t4.z + t4.w * t4.w;
            }
            ss = red8(ss);
            if (act && q == 0) {
                float nn = fmaxf(sqrtf(ss), EPSF);
                float sv = tanhf(nn) / nn;
                sc_l[m] = sv;
                x2_l[m] = ss * sv * sv;
            }
        }
    }

    const float* xsf = (const float*)xs4;
    const int    lh  = lane >> 1, lb = (lane & 1) * 2;   // dim-layout addressing

    // ---- init: per-wave partial Euclidean mean over OWN slots (zeros beyond n)
    {
        float2 S; S.x = 0.f; S.y = 0.f;
#pragma unroll
        for (int k = 0; k < 16; ++k) {
            int m = wv * 16 + k;
            float2 xv = *(const float2*)&xsf[(m * 32 + (lh ^ (m & 7))) * 4 + lb];
            S.x += xv.x; S.y += xv.y;
        }
        for (int mb = SLOTS + wv * 16; mb < n; mb += 64) {
            for (int k = 0; k < 16; ++k) {
                int m = mb + k;
                if (m < n) {
                    float2 rv = reps2[(size_t)mlist[m] * 64 + lane];
                    float s = sc_l[m];
                    S.x += s * rv.x; S.y += s * rv.y;
                }
            }
        }
        *(float2*)&part[1][wv][2 * lane] = S;
    }
    __syncthreads();                     // init-combine barrier
    float2 muf; float mu2;
    {
        float2 T; T.x = 0.f; T.y = 0.f;
#pragma unroll
        for (int w2 = 0; w2 < 4; ++w2) {
            float2 pv = *(const float2*)&part[1][w2][2 * lane];
            T.x += pv.x; T.y += pv.y;
        }
        muf.x = T.x * inv_cnt; muf.y = T.y * inv_cnt;
        float m2  = wsum64(muf.x * muf.x + muf.y * muf.y);
        float nrm = fmaxf(sqrtf(m2), EPSF);
        float fac = fminf(1.0f, MAXNORM / nrm);
        muf.x *= fac; muf.y *= fac;
        mu2 = m2 * fac * fac;
        *(float2*)&mu_lds[2 * lane] = muf;   // all waves, same values
    }

    // ---- Karcher iterations: ONE barrier each
    for (int it = 0; it < ITERS; ++it) {
        const int buf = it & 1;
        const float4* mu4 = (const float4*)mu_lds;
        float4 ms[4];
#pragma unroll
        for (int j = 0; j < 4; ++j) ms[j] = mu4[4 * q + j];

        // phase 1: own 2 slots, dots from registers (rows already expmapped)
        {
            float d   = red8(dot16(rA, ms));
            float x2v = x2_l[mA];
            float ca  = 1.0f - 2.0f * d + mu2;
            float cbv = 1.0f - x2v;
            float den = fmaxf(1.0f - 2.0f * d + x2v * mu2, EPSF);
            float iv  = 1.0f / den;
            bool  act = (mA < n);
            if (q == 0) { w_l[mA] = act ? ca * iv : 0.f; cb_l[mA] = act ? cbv * iv : 0.f; }
        }
        {
            float d   = red8(dot16(rB, ms));
            float x2v = x2_l[mB];
            float ca  = 1.0f - 2.0f * d + mu2;
            float cbv = 1.0f - x2v;
            float den = fmaxf(1.0f - 2.0f * d + x2v * mu2, EPSF);
            float iv  = 1.0f / den;
            bool  act = (mB < n);
            if (q == 0) { w_l[mB] = act ? ca * iv : 0.f; cb_l[mB] = act ? cbv * iv : 0.f; }
        }
        for (int mb = SLOTS + wv * 16; mb < n; mb += 64) {
#pragma unroll
            for (int t = 0; t < 2; ++t) {
                int  m   = mb + grp + 8 * t;
                bool act = (m < n);
                int  b   = act ? mlist[m] : 0;
                float dd = 0.f;
#pragma unroll
                for (int j = 0; j < 4; ++j) {
                    float4 a = reps4[(size_t)b * 32 + 4 * q + j];
                    dd += a.x * ms[j].x + a.y * ms[j].y + a.z * ms[j].z + a.w * ms[j].w;
                }
                dd = red8(dd);
                if (act) {
                    float dp  = sc_l[m] * dd;
                    float x2v = x2_l[m];
                    float ca  = 1.0f - 2.0f * dp + mu2;
                    float cbv = 1.0f - x2v;
                    float den = fmaxf(1.0f - 2.0f * dp + x2v * mu2, EPSF);
                    float iv  = 1.0f / den;
                    if (q == 0) { w_l[m] = ca * iv; cb_l[m] = cbv * iv; }
                }
            }
        }

        // phase C: own slots, lane = dim weighted row sum (wave-local w_l)
        float2 S2; S2.x = 0.f; S2.y = 0.f;
        float  scb = 0.f;
#pragma unroll
        for (int k = 0; k < 16; ++k) {
            int m = wv * 16 + k;
            float wvv = w_l[m];
            scb += cb_l[m];
            float2 xv = *(const float2*)&xsf[(m * 32 + (lh ^ (m & 7))) * 4 + lb];
            S2.x += wvv * xv.x; S2.y += wvv * xv.y;
        }
        for (int mb = SLOTS + wv * 16; mb < n; mb += 64) {
            for (int k = 0; k < 16; ++k) {
                int m = mb + k;
                if (m < n) {
                    float wvv = w_l[m] * sc_l[m];     // weight on RAW row
                    scb += cb_l[m];
                    float2 rv = reps2[(size_t)mlist[m] * 64 + lane];
                    S2.x += wvv * rv.x; S2.y += wvv * rv.y;
                }
            }
        }
        *(float2*)&part[buf][wv][2 * lane] = S2;
        if (lane == 0) scbp[buf][wv] = scb;
        __syncthreads();                 // THE barrier

        // combine + mobius (redundant on every wave)
        float2 T; T.x = 0.f; T.y = 0.f;
#pragma unroll
        for (int w2 = 0; w2 < 4; ++w2) {
            float2 pv = *(const float2*)&part[buf][w2][2 * lane];
            T.x += pv.x; T.y += pv.y;
        }
        float scbt = scbp[buf][0] + scbp[buf][1] + scbp[buf][2] + scbp[buf][3];
        float scs  = scbt * inv_cnt;
        float2 md;
        md.x = T.x * inv_cnt - scs * muf.x;
        md.y = T.y * inv_cnt - scs * muf.y;

        float A0 = md.x * md.x + md.y * md.y;
        float A1 = muf.x * md.x + muf.y * md.y;
        wsum64_2(A0, A1);
        float ca  = 1.0f + 2.0f * A1 + A0;
        float cbv = 1.0f - mu2;
        float den = fmaxf(1.0f + 2.0f * A1 + mu2 * A0, EPSF);
        float iv  = 1.0f / den;
        float2 tv;
        tv.x = (ca * muf.x + cbv * md.x) * iv;
        tv.y = (ca * muf.y + cbv * md.y) * iv;
        float t2   = (ca * ca * mu2 + 2.0f * ca * cbv * A1 + cbv * cbv * A0) * iv * iv;
        float nrm2 = fmaxf(sqrtf(t2), EPSF);
        float fc   = fminf(1.0f, MAXNORM / nrm2);
        muf.x = tv.x * fc; muf.y = tv.y * fc;
        mu2   = t2 * fc * fc;
        *(float2*)&mu_lds[2 * lane] = muf;   // same values from all waves
    }

    // final project_to_ball + store (wave 0)
    {
        float nf = fmaxf(sqrtf(mu2), EPSF);
        float ff = fminf(1.0f, MAXNORM / nf);
        muf.x *= ff; muf.y *= ff;
        mu2 = mu2 * ff * ff;
    }
    if (wv == 0) {
        ((float2*)(mu_out + (size_t)p * D_N))[lane] = muf;
        if (lane == 0) mu2_out[p] = mu2;
    }
}

// ---------------------------------------------------------------------------
// Kernel 2: distances + Pearson, fused. 8 blocks x 1024 threads, thread=pair.
// ---------------------------------------------------------------------------
__global__ __launch_bounds__(1024) void distcorr_kernel(
        const float* __restrict__ mu,
        const float* __restrict__ mu2s,
        const int*   __restrict__ dT,
        double* __restrict__ gpart,
        int*    __restrict__ counter,
        float*  __restrict__ out) {
    __shared__ float  lmu[P_N * 129];
    __shared__ float  lmu2[P_N];
    __shared__ double sh[16][5];
    __shared__ int    s_last;

    const int tid = threadIdx.x;
#pragma unroll
    for (int e = 0; e < 16; ++e) {
        int idx = tid + e * 1024;
        lmu[(idx >> 7) * 129 + (idx & 127)] = mu[idx];
    }
    if (tid < P_N) lmu2[tid] = mu2s[tid];
    __syncthreads();

    int k = blockIdx.x * 1024 + tid;
    double p0 = 0.0, p1 = 0.0, p2 = 0.0, p3 = 0.0, p4 = 0.0;
    if (k < NPAIRS) {
        int i = (int)(127.5f - sqrtf(127.5f * 127.5f - 2.0f * (float)k));
        if (i < 0) i = 0;
        while ((i + 1) * (2 * P_N - i - 2) / 2 <= k) ++i;
        while (i * (2 * P_N - i - 1) / 2 > k) --i;
        int j = k - i * (2 * P_N - i - 1) / 2 + i + 1;

        const float* ra = &lmu[i * 129];
        const float* rb = &lmu[j * 129];
        float a0 = 0.f, a1 = 0.f, a2 = 0.f, a3 = 0.f;
#pragma unroll
        for (int d = 0; d < D_N; d += 4) {
            float f0 = ra[d]     - rb[d];
            float f1 = ra[d + 1] - rb[d + 1];
            float f2 = ra[d + 2] - rb[d + 2];
            float f3 = ra[d + 3] - rb[d + 3];
            a0 += f0 * f0; a1 += f1 * f1; a2 += f2 * f2; a3 += f3 * f3;
        }
        float d2 = (a0 + a1) + (a2 + a3);
        float ai = fmaxf(1.f - lmu2[i], EPSF);
        float aj = fmaxf(1.f - lmu2[j], EPSF);
        float z  = 1.f + 2.f * d2 / fmaxf(ai * aj, EPSF);
        z = fmaxf(z, 1.f + EPSF);
        float dist = acoshf(z);
        double bb = (double)dist;
        double tt = (double)dT[k];
        p0 = bb; p1 = bb * bb; p2 = tt; p3 = tt * tt; p4 = bb * tt;
    }
    p0 = wred64d(p0); p1 = wred64d(p1); p2 = wred64d(p2);
    p3 = wred64d(p3); p4 = wred64d(p4);
    const int wid = tid >> 6, lane = tid & 63;
    if (lane == 0) {
        sh[wid][0] = p0; sh[wid][1] = p1; sh[wid][2] = p2;
        sh[wid][3] = p3; sh[wid][4] = p4;
    }
    __syncthreads();
    if (tid == 0) {
        double b0 = 0, b1 = 0, b2 = 0, b3 = 0, b4 = 0;
        for (int w = 0; w < 16; ++w) {
            b0 += sh[w][0]; b1 += sh[w][1]; b2 += sh[w][2];
            b3 += sh[w][3]; b4 += sh[w][4];
        }
        double* gp = gpart + (size_t)blockIdx.x * 5;
        gp[0] = b0; gp[1] = b1; gp[2] = b2; gp[3] = b3; gp[4] = b4;
        __threadfence();
        int old = atomicAdd(counter, 1);
        s_last = (old == (int)gridDim.x - 1) ? 1 : 0;
    }
    __syncthreads();
    if (!s_last) return;
    if (tid == 0) {
        __threadfence();
        double t0 = 0, t1 = 0, t2 = 0, t3 = 0, t4 = 0;
        for (int b = 0; b < 8; ++b) {
            t0 += gpart[b * 5 + 0]; t1 += gpart[b * 5 + 1]; t2 += gpart[b * 5 + 2];
            t3 += gpart[b * 5 + 3]; t4 += gpart[b * 5 + 4];
        }
        const double nn = (double)NPAIRS;
        double mb  = t0 / nn;
        double mt  = t2 / nn;
        double cov = t4 - nn * mb * mt;
        double vb  = t1 - nn * mb * mb;
        double vt  = t3 - nn * mt * mt;
        double corr = cov / sqrt(vb * vt);
        double res  = isnan(corr) ? 1.0 : (1.0 - corr);
        out[0] = (float)res;
    }
}

// ---------------------------------------------------------------------------
extern "C" void kernel_launch(void* const* d_in, const int* in_sizes, int n_in,
                              void* d_out, int out_size, void* d_ws, size_t ws_size,
                              hipStream_t stream) {
    const float* reps    = (const float*)d_in[0];
    const int*   targets = (const int*)d_in[1];
    const int*   dT      = (const int*)d_in[2];
    float* out = (float*)d_out;

    double* gpart   = (double*)d_ws;                          // 8*5 doubles
    int*    counter = (int*)((char*)d_ws + 320);              // 1 int
    float*  mu      = (float*)((char*)d_ws + 384);            // P*D floats
    float*  mu2s    = mu + (size_t)P_N * D_N;                 // P floats

    proto_kernel<<<P_N, 256, 0, stream>>>(reps, targets, mu, mu2s, counter);
    distcorr_kernel<<<8, 1024, 0, stream>>>(mu, mu2s, dT, gpart, counter, out);
}